// Round 11
// baseline (119.755 us; speedup 1.0000x reference)
//
#include <hip/hip_runtime.h>
#include <math.h>

#pragma clang fp contract(off)

#define NB 128
#define NA 8732
#define NAP 8736          // padded u16 key row stride (16B-aligned rows)
#define NC 21
#define TOPK 200
#define BCAP 512
#define CONF_T 0.01
#define NMS_T 0.045
#define NV (NAP / 8)      // 1092 uint4 (8 u16 keys) per class row
#define HSIZE 904         // coarse buckets = u16 key codes; real x in [35,897]
#define CHN 226           // HSIZE/4 chunk sums
#define CHPAD 232         // CHN padded to multiple of 8
#define CH2N 29           // CHPAD/8 super-chunks (32 buckets each)
#define SHN ((NC - 1) * 32)   // per-(b,c) super-chunk histogram width = 640/row-pair

// ---------------------------------------------------------------------------
// exact f64 masked softmax score, self-contained from conf (op order == np ref)
// (used by the tiny-ws fallback and the no-aux path)
// ---------------------------------------------------------------------------
__device__ __forceinline__ double exact_score_cf(const float* __restrict__ conf,
                                                 int b, int i, int c) {
  const float* row = conf + ((size_t)b * NA + i) * NC;
  float r[NC];
#pragma unroll
  for (int k = 0; k < NC; ++k) r[k] = row[k];
  float mx = r[0];
#pragma unroll
  for (int k = 1; k < NC; ++k) mx = fmaxf(mx, r[k]);
  double d = 0.0;
#pragma unroll
  for (int k = 0; k < NC; ++k) d += exp((double)r[k] - (double)mx);
  double s = exp((double)r[c] - (double)mx) / d;
  return (s > CONF_T) ? s : 0.0;
}

// cheap exact score via packed per-row aux {denominator, max}: one 16B load.
// bit-identical to exact_score_cf (same fmaxf chain widened exactly to f64,
// same k-ordered f64 denominator sum).
__device__ __forceinline__ double exact_score_aux(const float* __restrict__ conf,
                                                  const double2* __restrict__ aux,
                                                  int b, int i, int c) {
  size_t r = (size_t)b * NA + i;
  double v = (double)conf[r * NC + c];
  double2 a = aux[r];                 // a.x = denom, a.y = (double)mx
  double s = exp(v - a.y) / a.x;
  return (s > CONF_T) ? s : 0.0;
}

__device__ __forceinline__ double exact_score(const float* __restrict__ conf,
                                              const double2* __restrict__ aux,
                                              int use_aux, int b, int i, int c) {
  if (use_aux) return exact_score_aux(conf, aux, b, i, c);
  return exact_score_cf(conf, b, i, c);
}

// f64 decode of one box (op order == np ref)
__device__ __forceinline__ void decode64(const float* __restrict__ loc,
                                         const float* __restrict__ anchors,
                                         int b, int ai, double* o) {
  const float* lp = loc + ((size_t)b * NA + ai) * 4;
  const float* ap = anchors + (size_t)ai * 4;
  double l0 = (double)lp[0], l1 = (double)lp[1];
  double l2 = (double)lp[2], l3 = (double)lp[3];
  double a0 = (double)ap[0], a1 = (double)ap[1];
  double a2 = (double)ap[2], a3 = (double)ap[3];
  double cx = a0 + (l0 * 0.1) * a2;
  double cy = a1 + (l1 * 0.1) * a3;
  double w = a2 * exp(l2 * 0.2);
  double h = a3 * exp(l3 * 0.2);
  o[0] = cx - 0.5 * w; o[1] = cy - 0.5 * h;
  o[2] = cx + 0.5 * w; o[3] = cy + 0.5 * h;
}

__device__ __forceinline__ bool entBefore(double sa, int ia, double sb, int ib) {
  return (sa > sb) || (sa == sb && ia < ib);
}

// suffix-inclusive sum across a 64-lane wave; lanes holding no value must pass 0
__device__ __forceinline__ unsigned wave_suffix_sum(unsigned v, int lane) {
#pragma unroll
  for (int off = 1; off < 64; off <<= 1) {
    unsigned o = (unsigned)__shfl_down((int)v, off);
    v += (lane + off < 64) ? o : 0u;
  }
  return v;
}

// ---------------------------------------------------------------------------
// k_prep: u16 softmax keys (top 16 f32 bits; bucket machinery only ever uses
// bits [30:16]) + packed per-row aux {f64 denominator, f64(max)} + EXACT
// per-(b,c) 32-bin super-chunk histogram (block-aggregated in LDS, flushed
// with global atomics). k_fast derives its histogram lower bound L from this
// exactly -- no sampling, no redo, tighter filter.
// ---------------------------------------------------------------------------
__global__ __launch_bounds__(256) void k_prep(const float* __restrict__ conf,
                                              unsigned short* __restrict__ scores,
                                              double2* __restrict__ aux,
                                              unsigned* __restrict__ shist,
                                              int do_aux) {
  __shared__ float rows[256 * NC];
  __shared__ unsigned sh[2 * SHN];   // block may span 2 batches (NA % 256 != 0)
  int base = blockIdx.x * 256;                  // NB*NA == 4366*256 exactly
  const float4* src = (const float4*)(conf + (size_t)base * NC);
  float4* dst = (float4*)rows;
  for (int t = threadIdx.x; t < (256 * NC) / 4; t += 256) dst[t] = src[t];
  for (int t = threadIdx.x; t < 2 * SHN; t += 256) sh[t] = 0u;
  __syncthreads();
  int g = base + threadIdx.x;
  const float* row = rows + threadIdx.x * NC;
  float v[NC];
#pragma unroll
  for (int k = 0; k < NC; ++k) v[k] = row[k];
  float mx = v[0];
#pragma unroll
  for (int k = 1; k < NC; ++k) mx = fmaxf(mx, v[k]);
  float e[NC], s = 0.0f;
#pragma unroll
  for (int k = 0; k < NC; ++k) {
    e[k] = expf(v[k] - mx);
    s += e[k];
  }
  float inv = 1.0f / s;
  int b = g / NA, i = g - b * NA;
  int b_first = base / NA;
  int dz = (b - b_first) * SHN;
#pragma unroll
  for (int cc = 1; cc < NC; ++cc) {
    float sc = e[cc] * inv;
    unsigned short key =
        (sc > 0.0099f) ? (unsigned short)(__float_as_uint(sc) >> 16)
                       : (unsigned short)0;
    scores[(size_t)(b * (NC - 1) + (cc - 1)) * NAP + i] = key;
    if (key)   // nonzero keys: x = key-0x3BFF in [35,897] -> bin in [1,28]
      atomicAdd(&sh[dz + (cc - 1) * 32 + (((int)key - 0x3BFF) >> 5)], 1u);
  }
  if (do_aux) {
    double d = 0.0;
#pragma unroll
    for (int k = 0; k < NC; ++k) d += exp((double)v[k] - (double)mx);
    aux[g] = make_double2(d, (double)mx);   // coalesced 16B
  }
  __syncthreads();
  // flush block-aggregated bins (zero bins skipped; d0=1 bins are all zero
  // when the block doesn't span into b_first+1)
  for (int t = threadIdx.x; t < 2 * SHN; t += 256) {
    unsigned cnt = sh[t];
    if (cnt) {
      int d0 = t / SHN;
      int rem = t - d0 * SHN;
      atomicAdd(&shist[(size_t)(b_first + d0) * SHN + rem], cnt);
    }
  }
}

// zero the key-row pads, the class-0 output rows, and the shist array
__global__ __launch_bounds__(256) void k_pad(unsigned short* __restrict__ scores,
                                             float* __restrict__ out,
                                             unsigned* __restrict__ shist) {
  int t = blockIdx.x * 256 + threadIdx.x;
  if (t < NB * TOPK * 5) {
    int bb = t / (TOPK * 5);
    int r = t - bb * (TOPK * 5);
    out[(size_t)bb * NC * TOPK * 5 + r] = 0.0f;
  }
  if (t < NB * (NC - 1)) {
    unsigned short* p = scores + (size_t)t * NAP + NA;
    p[0] = 0; p[1] = 0; p[2] = 0; p[3] = 0;
  }
  if (t < NB * SHN) shist[t] = 0u;
}

// ---------------------------------------------------------------------------
// k_fast: one 256-thread block per (b,c>=1), XCD-swizzled, 8 blocks/CU.
// Exact L from k_prep's shist (one coalesced 128B read; suffix(L) >= TOPK
// guaranteed -> redo never fires), streaming u16 keys (R5-proven two-pass),
// wave-parallel scans, sort-free top-K via suffix-sum direct placement,
// f32 output decode + parallel f64 decode to LDS for the exact NMS guard,
// lazy greedy NMS.
// ---------------------------------------------------------------------------
__global__ __launch_bounds__(256, 8) void k_fast(const float* __restrict__ loc,
                                                 const float* __restrict__ conf,
                                                 const float* __restrict__ anchors,
                                                 const unsigned short* __restrict__ scores,
                                                 const double2* __restrict__ aux,
                                                 const unsigned* __restrict__ shist,
                                                 float* __restrict__ out,
                                                 int use_aux) {
  int id = blockIdx.x;
  int xcd = id & 7, slot0 = id >> 3;    // same-b classes share an XCD
  int c = 1 + (slot0 % (NC - 1));
  int b = (slot0 / (NC - 1)) * 8 + xcd;
  int tid = threadIdx.x;
  float* outbase = out + ((size_t)(b * NC + c)) * TOPK * 5;

  __shared__ unsigned hist[HSIZE];    // counts -> (atomicSub) cursors; radix reuses [0:256)
  __shared__ unsigned chunk[CHPAD];   // 4-bucket sums (padded with zeros)
  __shared__ unsigned chunk2[32];     // excl. suffix over super-chunks
  union U2 {  // boundary phase vs f64 boxes for NMS guard (disjoint in time)
    struct { double bnds[BCAP]; int bndi[BCAP]; } bb;  // 6144 B
    double dbox[TOPK][4];                              // 6400 B
  };
  __shared__ U2 u2;
  union U3 {  // selection phase vs NMS phase (disjoint in time)
    unsigned suf[HSIZE];                                   // 3616 B
    struct { float4 fbox[TOPK]; float farea[TOPK]; } fb;   // 4000 B
  };
  __shared__ U3 u3;
  __shared__ double ssel[256];
  __shared__ int isel[256];
  __shared__ unsigned keepw[7];
  __shared__ int ctl_cnt, ctl_m, ctl_n1, ctl_kneed, ctl_lo, ctl_hi, ctl_k;
  __shared__ int ctl_fix, ctl_redo;
  __shared__ unsigned ctl_pref, ctl_L;

  const unsigned short* srow =
      scores + (size_t)(b * (NC - 1) + (c - 1)) * NAP;
  const uint4* sv = (const uint4*)srow;

  // ---- P0: init; wave 0 derives EXACT L from shist (coalesced 128B read).
  //      L = lower edge of the super-chunk containing D: suffix >= TOPK by
  //      construction, so the filtered histogram always reaches TOPK. ----
  for (int t = tid; t < TOPK; t += 256) isel[t] = 0;   // safety vs stale slots
  if (tid == 0) { ctl_cnt = 0; ctl_m = 0; ctl_fix = 0; }
  if (tid < 64) {
    const unsigned* shrow = shist + (size_t)(b * (NC - 1) + (c - 1)) * 32;
    unsigned h = (tid < 32) ? shrow[tid] : 0u;   // bins 29..31 always 0
    unsigned s = wave_suffix_sum(h, tid);
    unsigned long long bal = __ballot((int)(tid < 32 && s >= (unsigned)TOPK));
    if (tid == 0) {
      int w = bal ? (63 - (int)__clzll(bal)) : -1;   // -1: sparse (<TOPK keys)
      ctl_L = (w >= 1) ? (unsigned)(0x3BFF + (w << 5)) : 0u;
    }
  }
  __syncthreads();

  // ---- P1..P4: filtered histogram -> wave-parallel D-scan (redo is a
  //      never-fires safety net now that L is exact) ----
  unsigned L16x = ctl_L ? ctl_L : 1u;
  int lo, hi, n1, kneed;
  for (;;) {
    for (int t = tid; t < HSIZE; t += 256) hist[t] = 0u;
    if (tid == 0) ctl_redo = 0;
    __syncthreads();
    // P1: histogram keys >= L only. Invariant: nonzero keys have
    // x = key-0x3BFF in [35,897] (masked softmax in (0.0099, ~1.004]),
    // so no bucket clamps are needed.
    for (int q = tid; q < NV; q += 256) {
      uint4 v = sv[q];
      unsigned ks[8] = {v.x & 0xFFFFu, v.x >> 16, v.y & 0xFFFFu, v.y >> 16,
                        v.z & 0xFFFFu, v.z >> 16, v.w & 0xFFFFu, v.w >> 16};
#pragma unroll
      for (int t = 0; t < 8; ++t) {
        if (ks[t] >= L16x) atomicAdd(&hist[(int)ks[t] - 0x3BFF], 1u);
      }
    }
    __syncthreads();
    // P2: chunk sums (4 buckets each), pad to CHPAD with zeros
    if (tid < CHN) {
      unsigned csum = 0;
#pragma unroll
      for (int j = 0; j < 4; ++j) csum += hist[tid * 4 + j];
      chunk[tid] = csum;
    } else if (tid < CHPAD) {
      chunk[tid] = 0u;
    }
    __syncthreads();
    // P3+P4 fused on wave 0: super-chunk sums, suffix scans, D-scan, and
    // exclusive-suffix conversion — all via shfl/ballot.
    if (tid < 64) {
      int lane = tid;
      unsigned h2 = 0;
      if (lane < CH2N) {
        int cb = lane * 8;
#pragma unroll
        for (int j = 0; j < 8; ++j) h2 += chunk[cb + j];
      }
      unsigned s2 = wave_suffix_sum(h2, lane);
      unsigned long long bal = __ballot((int)(lane < CH2N && s2 >= (unsigned)TOPK));
      int t2 = bal ? (63 - (int)__clzll(bal)) : -1;
      if (t2 < 0 && L16x > 1u) {
        if (lane == 0) ctl_redo = 1;   // safety net (exact L: never taken)
      } else {
        if (t2 < 0) {
          // genuinely sparse: fewer than TOPK nonzero keys (total = s2 @ lane 0)
          if (lane == 0) {
            ctl_lo = 1; ctl_hi = 0; ctl_n1 = (int)s2; ctl_kneed = TOPK - (int)s2;
          }
        } else {
          unsigned cumS = (unsigned)__shfl((int)(s2 - h2), t2);  // count(>super t2)
          unsigned hc = (lane < 8) ? chunk[t2 * 8 + lane] : 0u;
          unsigned sc = wave_suffix_sum(hc, lane);
          unsigned long long balc =
              __ballot((int)(lane < 8 && cumS + sc >= (unsigned)TOPK));
          int jc = 63 - (int)__clzll(balc);
          int tc = t2 * 8 + jc;
          unsigned cumC = cumS + (unsigned)__shfl((int)(sc - hc), jc);
          unsigned hb = (lane < 4) ? hist[tc * 4 + lane] : 0u;
      unsigned sb = wave_suffix_sum(hb, lane);
          unsigned long long balb =
              __ballot((int)(lane < 4 && cumC + sb >= (unsigned)TOPK));
          int jb = 63 - (int)__clzll(balb);
          int D = tc * 4 + jb;
          unsigned cum = cumC + (unsigned)__shfl((int)(sb - hb), jb);  // count(>D)
          int hi_ = (D + 1 < HSIZE) ? D + 1 : D;
          int lo_ = (D - 1 >= 1) ? D - 1 : D;
          unsigned hup = (hi_ > D) ? hist[hi_] : 0u;
          if (lane == 0) {
            ctl_lo = lo_; ctl_hi = hi_;
            ctl_n1 = (int)(cum - hup);        // count(buckets > hi)
            ctl_kneed = TOPK - ctl_n1;
          }
        }
        if (lane < 32) chunk2[lane] = s2 - h2;   // exclusive suffix (super level)
      }
    }
    __syncthreads();
    if (!ctl_redo) break;
    L16x = 1u;
  }
  lo = ctl_lo; hi = ctl_hi; n1 = ctl_n1; kneed = ctl_kneed;

  // ---- P5: full per-bucket suffix sums: suf[x] = #keys in buckets > x ----
  if (tid < CHN) {
    unsigned s = chunk2[tid >> 3];
    int ge = ((tid >> 3) + 1) << 3;
    for (int u = tid + 1; u < ge; ++u) s += chunk[u];  // padded zeros safe
    int b0 = tid * 4;
    unsigned h3 = hist[b0 + 3], h2 = hist[b0 + 2], h1 = hist[b0 + 1];
    u3.suf[b0 + 3] = s;
    u3.suf[b0 + 2] = s + h3;
    u3.suf[b0 + 1] = s + h3 + h2;
    u3.suf[b0 + 0] = s + h3 + h2 + h1;
  }
  __syncthreads();

  // ---- P7: collect (stream from L1/L2). Certain (bucket > hi): direct to
  //      final bucket span via atomicSub cursor on hist (counts exact for
  //      x > hi; no clear pass). Boundary band [lo..hi] -> bndi. The stream
  //      is UNFILTERED (key-threshold compares), so band members below L
  //      are always collected -- the L-filter cannot lose them. ----
  {
    unsigned tC16 = (unsigned)(0x3C00 + hi);   // key16 >= tC16 <=> bucket > hi
    unsigned tB16 = (unsigned)(0x3BFF + lo);   // key16 >= tB16 <=> bucket >= lo
    for (int q = tid; q < NV; q += 256) {
      uint4 v = sv[q];
      unsigned ks[8] = {v.x & 0xFFFFu, v.x >> 16, v.y & 0xFFFFu, v.y >> 16,
                        v.z & 0xFFFFu, v.z >> 16, v.w & 0xFFFFu, v.w >> 16};
#pragma unroll
      for (int t = 0; t < 8; ++t) {
        unsigned key = ks[t];
        if (key >= tC16) {
          int x = (int)key - 0x3BFF;
          int slot = (int)u3.suf[x] + (int)atomicSub(&hist[x], 1u) - 1;
          if (slot < TOPK) isel[slot] = (x << 16) | (q * 8 + t);  // packed
        } else if (key >= tB16) {
          int p = atomicAdd(&ctl_m, 1);
          if (p < BCAP) u2.bb.bndi[p] = q * 8 + t;
        }
      }
    }
  }
  __syncthreads();
  int m = (hi > 0) ? ctl_m : 0;

  if (hi > 0 && m > BCAP) {
    // ---- overflow fallback: exact 2-pass u16 radix + full bitonic (~never) ----
    if (tid == 0) { ctl_k = TOPK; ctl_pref = 0u; }
    __syncthreads();
    for (int shift = 8; shift >= 0; shift -= 8) {
      hist[tid] = 0u;
      __syncthreads();
      unsigned pref = ctl_pref;
      for (int q = tid; q < NV; q += 256) {
        uint4 v = sv[q];
        unsigned ks[8] = {v.x & 0xFFFFu, v.x >> 16, v.y & 0xFFFFu, v.y >> 16,
                          v.z & 0xFFFFu, v.z >> 16, v.w & 0xFFFFu, v.w >> 16};
#pragma unroll
        for (int t = 0; t < 8; ++t) {
          unsigned key = ks[t];
          if (key == 0u) continue;
          bool match = (shift == 8) || ((key >> 8) == (pref >> 8));
          if (match) atomicAdd(&hist[(key >> shift) & 255u], 1u);
        }
      }
      __syncthreads();
      if (tid == 0) {
        int k = ctl_k;
        unsigned cum = 0;
        int d = 255;
        for (; d > 0; --d) {
          unsigned h = hist[d];
          if (cum + h >= (unsigned)k) break;
          cum += h;
        }
        ctl_k = k - (int)cum;
        ctl_pref = pref | ((unsigned)d << shift);
      }
      __syncthreads();
    }
    unsigned Tf = ctl_pref;
    kneed = ctl_k;
    n1 = TOPK - kneed;
    if (tid == 0) { ctl_cnt = 0; ctl_m = 0; }
    __syncthreads();
    for (int q = tid; q < NV; q += 256) {
      uint4 v = sv[q];
      unsigned ks[8] = {v.x & 0xFFFFu, v.x >> 16, v.y & 0xFFFFu, v.y >> 16,
                        v.z & 0xFFFFu, v.z >> 16, v.w & 0xFFFFu, v.w >> 16};
#pragma unroll
      for (int t = 0; t < 8; ++t) {
        unsigned key = ks[t];
        if (key > Tf) {
          int p = atomicAdd(&ctl_cnt, 1);
          if (p < 256) isel[p] = q * 8 + t;   // raw idx
        } else if (key == Tf) {
          int p = atomicAdd(&ctl_m, 1);
          if (p < BCAP) u2.bb.bndi[p] = q * 8 + t;
        }
      }
    }
    __syncthreads();
    m = ctl_m;
    if (m > BCAP) m = BCAP;
    for (int q = tid; q < m; q += 256)
      u2.bb.bnds[q] = exact_score(conf, aux, use_aux, b, u2.bb.bndi[q], c);
    __syncthreads();
    for (int q = tid; q < m; q += 256) {
      double sq = u2.bb.bnds[q];
      int iq = u2.bb.bndi[q];
      int rank = 0;
      for (int r = 0; r < m; ++r)
        if (entBefore(u2.bb.bnds[r], u2.bb.bndi[r], sq, iq)) ++rank;
      if (rank < kneed) { isel[n1 + rank] = iq; ssel[n1 + rank] = sq; }
    }
    __syncthreads();
    if (tid < TOPK) {
      if (tid < n1) ssel[tid] = exact_score(conf, aux, use_aux, b, isel[tid], c);
    } else {
      ssel[tid] = -1.0;
      isel[tid] = 0x7fffffff;
    }
    // bitonic sort 256: (score desc, index asc)
    for (int kk = 2; kk <= 256; kk <<= 1) {
      for (int j = kk >> 1; j > 0; j >>= 1) {
        __syncthreads();
        int ixj = tid ^ j;
        if (ixj > tid) {
          double s1 = ssel[tid], s2 = ssel[ixj];
          int i1 = isel[tid], i2 = isel[ixj];
          bool up = ((tid & kk) == 0);
          bool sw = up ? entBefore(s2, i2, s1, i1) : entBefore(s1, i1, s2, i2);
          if (sw) {
            ssel[tid] = s2; ssel[ixj] = s1;
            isel[tid] = i2; isel[ixj] = i1;
          }
        }
      }
    }
    __syncthreads();
  } else {
    // ---- main path: sort-free ranking ----
    // P8a: exact scores. certain at temp slot tid (<n1); boundary into bnds.
    if (tid < n1)
      ssel[tid] = exact_score(conf, aux, use_aux, b, isel[tid] & 0xFFFF, c);
    if (hi > 0) {
      for (int q = tid; q < m; q += 256)
        u2.bb.bnds[q] = exact_score(conf, aux, use_aux, b, u2.bb.bndi[q], c);
    }
    __syncthreads();
    // P8b: ranks. Certain: within-bucket exact rank (reads ssel/isel [0,n1)).
    //      Boundary: exact rank among m, writes [n1,200) (disjoint region).
    double myS = 0.0;
    int myI = 0, myPos = -1;
    if (tid < n1) {
      int packed = isel[tid];
      int bk = packed >> 16;
      myI = packed & 0xFFFF;
      myS = ssel[tid];
      int base = (int)u3.suf[bk];
      int len = (int)u3.suf[bk - 1] - base;
      int r = 0;
      for (int u = base; u < base + len; ++u) {
        if (u == tid) continue;
        double ps = ssel[u];
        int pI = isel[u] & 0xFFFF;
        if (entBefore(ps, pI, myS, myI)) ++r;
      }
      myPos = base + r;
    }
    if (hi > 0) {
      for (int q = tid; q < m; q += 256) {
        double sq = u2.bb.bnds[q];
        int iq = u2.bb.bndi[q];
        int rank = 0;
        for (int r = 0; r < m; ++r)
          if (entBefore(u2.bb.bnds[r], u2.bb.bndi[r], sq, iq)) ++rank;
        if (rank < kneed) { isel[n1 + rank] = iq; ssel[n1 + rank] = sq; }
      }
    } else {
      // sparse: zero-score dummies (keep=false downstream -> zero rows)
      for (int j = n1 + tid; j < TOPK; j += 256) {
        isel[j] = j - n1;
        ssel[j] = 0.0;
      }
    }
    __syncthreads();
    // P8c: certain final placement (exact within-bucket order)
    if (myPos >= 0 && myPos < TOPK) { ssel[myPos] = myS; isel[myPos] = myI; }
    __syncthreads();
    // P8d: exact-order guard. Inversions possible only for exact scores within
    // key error (~4e-6 rel) of a bucket edge; detect and (rarely) fix.
    if (tid < 64) {
      bool inv = false;
      for (int j = tid + 1; j < TOPK; j += 64)
        if (entBefore(ssel[j], isel[j], ssel[j - 1], isel[j - 1])) inv = true;
      unsigned long long bal = __ballot((int)inv);
      if (tid == 0 && bal != 0ull) ctl_fix = 1;
    }
    __syncthreads();
    if (ctl_fix) {
      if (tid == 0) {
        for (int a = 1; a < TOPK; ++a) {
          double s = ssel[a];
          int ii = isel[a];
          int p = a - 1;
          while (p >= 0 && entBefore(s, ii, ssel[p], isel[p])) {
            ssel[p + 1] = ssel[p]; isel[p + 1] = isel[p]; --p;
          }
          ssel[p + 1] = s; isel[p + 1] = ii;
        }
      }
      __syncthreads();
    }
  }

  // ---- decode own box: f32 for output/tier-1 (HW expf; matches f32
  //      reference op order -> absmax 0) AND parallel f64 to LDS dbox for
  //      the exact NMS guard (R5/R10-proven: guard = 8 LDS reads). ----
  float fx1 = 0, fy1 = 0, fx2 = 0, fy2 = 0;
  if (tid < TOPK) {
    int ai = isel[tid];
    const float* lp = loc + ((size_t)b * NA + ai) * 4;
    const float* ap = anchors + (size_t)ai * 4;
    float l0 = lp[0], l1 = lp[1], l2 = lp[2], l3 = lp[3];
    float a0 = ap[0], a1 = ap[1], a2 = ap[2], a3 = ap[3];
    float cx = a0 + (l0 * 0.1f) * a2;
    float cy = a1 + (l1 * 0.1f) * a3;
    float w = a2 * expf(l2 * 0.2f);
    float h = a3 * expf(l3 * 0.2f);
    fx1 = cx - 0.5f * w; fy1 = cy - 0.5f * h;
    fx2 = cx + 0.5f * w; fy2 = cy + 0.5f * h;
    u3.fb.fbox[tid] = make_float4(fx1, fy1, fx2, fy2);
    u3.fb.farea[tid] = (fx2 - fx1) * (fy2 - fy1);
    // f64 decode (reuses loaded lp/ap; software exps run in parallel
    // across 200 threads, once per block)
    double dcx = (double)a0 + ((double)l0 * 0.1) * (double)a2;
    double dcy = (double)a1 + ((double)l1 * 0.1) * (double)a3;
    double dw = (double)a2 * exp((double)l2 * 0.2);
    double dh = (double)a3 * exp((double)l3 * 0.2);
    u2.dbox[tid][0] = dcx - 0.5 * dw;
    u2.dbox[tid][1] = dcy - 0.5 * dh;
    u2.dbox[tid][2] = dcx + 0.5 * dw;
    u2.dbox[tid][3] = dcy + 0.5 * dh;
  }
  __syncthreads();

  // ---- lazy greedy NMS on wave 0: alive-mask ballots, jump to next kept
  //      row, IoU on the fly. f32 mult-compare (band 3e-4*uni covers f32
  //      arith + box-quantization error); tight cases decided in exact f64
  //      from LDS dbox -- decisions bit-identical to reference. ----
  if (tid < 64) {
    int l = tid;
    unsigned kr = 0u;
    float4 ob[4]; float oa[4];
#pragma unroll
    for (int q = 0; q < 4; ++q) {
      int j = l + 64 * q;
      if (j < TOPK) {
        if (ssel[j] > CONF_T) kr |= 1u << q;
        ob[q] = u3.fb.fbox[j];
        oa[q] = u3.fb.farea[j];
      } else {
        ob[q] = make_float4(0.0f, 0.0f, 0.0f, 0.0f);
        oa[q] = 0.0f;
      }
    }
    int cur = 0;
    while (cur < TOPK) {
      unsigned long long ms0 = __ballot((int)(kr & 1u));
      unsigned long long ms1 = __ballot((int)(kr & 2u));
      unsigned long long ms2 = __ballot((int)(kr & 4u));
      unsigned long long ms3 = __ballot((int)(kr & 8u));
      int q0 = cur >> 6;
      int sh = cur & 63;
      unsigned long long below = sh ? ((1ull << sh) - 1ull) : 0ull;
      unsigned long long t0 = (q0 == 0) ? (ms0 & ~below) : 0ull;
      unsigned long long t1 = (q0 < 1) ? ms1 : ((q0 == 1) ? (ms1 & ~below) : 0ull);
      unsigned long long t2 = (q0 < 2) ? ms2 : ((q0 == 2) ? (ms2 & ~below) : 0ull);
      unsigned long long t3 = (q0 < 3) ? ms3 : (ms3 & ~below);
      int i = TOPK;
      if (t0) i = __ffsll(t0) - 1;
      else if (t1) i = 64 + __ffsll(t1) - 1;
      else if (t2) i = 128 + __ffsll(t2) - 1;
      else if (t3) i = 192 + __ffsll(t3) - 1;
      if (i >= TOPK) break;          // no alive row left
      float4 fbi = u3.fb.fbox[i];    // LDS broadcast
      float fai = u3.fb.farea[i];
#pragma unroll
      for (int q = 0; q < 4; ++q) {
        int r = l + 64 * q;
        if (r > i && r < TOPK && ((kr >> q) & 1u)) {
          float lx = fmaxf(fbi.x, ob[q].x), ly = fmaxf(fbi.y, ob[q].y);
          float rx = fminf(fbi.z, ob[q].z), ry = fminf(fbi.w, ob[q].w);
          float iw = fmaxf(rx - lx, 0.0f), ih = fmaxf(ry - ly, 0.0f);
          float inter = iw * ih;
          float uni = fai + oa[q] - inter + 1e-12f;
          float diff = inter - 0.045f * uni;    // sign(diff) == sign(io-T)
          bool sup;
          if (fabsf(diff) < 3e-4f * uni) {      // |io-T| < 3e-4: decide in f64
            double ix1 = u2.dbox[i][0], iy1 = u2.dbox[i][1];
            double ix2 = u2.dbox[i][2], iy2 = u2.dbox[i][3];
            double jx1 = u2.dbox[r][0], jy1 = u2.dbox[r][1];
            double jx2 = u2.dbox[r][2], jy2 = u2.dbox[r][3];
            double dlx = fmax(ix1, jx1), dly = fmax(iy1, jy1);
            double drx = fmin(ix2, jx2), dry = fmin(iy2, jy2);
            double diw = drx - dlx; if (diw < 0.0) diw = 0.0;
            double dih = dry - dly; if (dih < 0.0) dih = 0.0;
            double dint = diw * dih;
            double dai = (ix2 - ix1) * (iy2 - iy1);
            double daj = (jx2 - jx1) * (jy2 - jy1);
            sup = dint > NMS_T * (dai + daj - dint + 1e-12);
          } else {
            sup = diff > 0.0f;
          }
          if (sup) kr &= ~(1u << q);
        }
      }
      cur = i + 1;
    }
#pragma unroll
    for (int q = 0; q < 4; ++q) {
      unsigned long long bal = __ballot((int)((kr >> q) & 1u));
      if (l == 0) {
        keepw[2 * q] = (unsigned)bal;
        if (2 * q + 1 < 7) keepw[2 * q + 1] = (unsigned)(bal >> 32);
      }
    }
  }
  __syncthreads();

  // ---- pack kept rows to the front, zero-fill the rest ----
  int nk = 0;
#pragma unroll
  for (int w = 0; w < 7; ++w) nk += __popc(keepw[w]);
  if (tid < TOPK) {
    int j = tid;
    bool kept = (keepw[j >> 5] >> (j & 31)) & 1u;
    if (kept) {
      int pos = 0;
      for (int w = 0; w < (j >> 5); ++w) pos += __popc(keepw[w]);
      pos += __popc(keepw[j >> 5] & ((1u << (j & 31)) - 1u));
      float* o = outbase + (size_t)pos * 5;
      o[0] = (float)ssel[j];
      o[1] = fx1;
      o[2] = fy1;
      o[3] = fx2;
      o[4] = fy2;
    }
    if (j >= nk) {
      float* o = outbase + (size_t)j * 5;
      o[0] = 0.0f; o[1] = 0.0f; o[2] = 0.0f; o[3] = 0.0f; o[4] = 0.0f;
    }
  }
}

// ===========================================================================
// Tiny-workspace fallback (R2-proven, self-contained) — only if ws too small
// ===========================================================================
__global__ __launch_bounds__(256) void k_main_nf(const float* __restrict__ loc,
                                                 const float* __restrict__ conf,
                                                 const float* __restrict__ anchors,
                                                 float* __restrict__ out) {
  int bc = blockIdx.x;
  int b = bc / NC;
  int c = bc % NC;
  int tid = threadIdx.x;
  float* outbase = out + (size_t)bc * TOPK * 5;
  if (c == 0) {
    for (int k = tid; k < TOPK * 5; k += 256) outbase[k] = 0.0f;
    return;
  }
  union U {
    float sf[NA];
    struct { double box[TOPK][4]; double area[TOPK]; } p2;
  };
  __shared__ U u;
  __shared__ double ssel[256];
  __shared__ int isel[256];
  __shared__ unsigned hist[256];
  __shared__ double bnds[256];
  __shared__ int bndi[256];
  __shared__ int keepL[256];
  __shared__ unsigned long long wmask[4];
  __shared__ int ctl_k, ctl_cnt, ctl_m;
  __shared__ unsigned ctl_pref;

  for (int i = tid; i < NA; i += 256)
    u.sf[i] = (float)exact_score_cf(conf, b, i, c);
  if (tid == 0) { ctl_k = TOPK; ctl_pref = 0u; }
  __syncthreads();
  for (int shift = 24; shift >= 0; shift -= 8) {
    hist[tid] = 0u;
    __syncthreads();
    unsigned pref = ctl_pref;
    for (int i = tid; i < NA; i += 256) {
      unsigned key = __float_as_uint(u.sf[i]);
      bool match = (shift == 24) || ((key >> (shift + 8)) == (pref >> (shift + 8)));
      if (match) atomicAdd(&hist[(key >> shift) & 255u], 1u);
    }
    __syncthreads();
    if (tid == 0) {
      int k = ctl_k;
      unsigned cum = 0;
      int d = 255;
      for (; d > 0; --d) {
        unsigned h = hist[d];
        if (cum + h >= (unsigned)k) break;
        cum += h;
      }
      ctl_k = k - (int)cum;
      ctl_pref = pref | ((unsigned)d << shift);
    }
    __syncthreads();
  }
  unsigned Tf = ctl_pref;
  int kneed = ctl_k;
  int n1 = TOPK - kneed;
  if (tid == 0) { ctl_cnt = 0; ctl_m = 0; }
  __syncthreads();
  for (int i = tid; i < NA; i += 256) {
    unsigned key = __float_as_uint(u.sf[i]);
    if (key > Tf) {
      int p = atomicAdd(&ctl_cnt, 1);
      if (p < 256) isel[p] = i;
    } else if (key == Tf && Tf != 0u) {
      int q = atomicAdd(&ctl_m, 1);
      if (q < 256) bndi[q] = i;
    }
  }
  __syncthreads();
  int zf;
  if (Tf == 0u) {
    zf = n1;
    for (int j = n1 + tid; j < TOPK; j += 256) isel[j] = j - n1;
  } else {
    zf = TOPK;
    int m = ctl_m;
    if (m > 256) m = 256;
    if (tid < m) bnds[tid] = exact_score_cf(conf, b, bndi[tid], c);
    __syncthreads();
    if (tid < m) {
      double sq = bnds[tid];
      int iq = bndi[tid];
      int rank = 0;
      for (int r = 0; r < m; ++r)
        if (entBefore(bnds[r], bndi[r], sq, iq)) ++rank;
      if (rank < kneed) isel[n1 + rank] = iq;
    }
  }
  __syncthreads();
  if (tid < TOPK) {
    ssel[tid] = (tid < zf) ? exact_score_cf(conf, b, isel[tid], c) : 0.0;
  } else {
    ssel[tid] = -1.0;
    isel[tid] = 0x7fffffff;
  }
  for (int kk = 2; kk <= 256; kk <<= 1) {
    for (int j = kk >> 1; j > 0; j >>= 1) {
      __syncthreads();
      int ixj = tid ^ j;
      if (ixj > tid) {
        double s1 = ssel[tid], s2 = ssel[ixj];
        int i1 = isel[tid], i2 = isel[ixj];
        bool up = ((tid & kk) == 0);
        bool sw = up ? entBefore(s2, i2, s1, i1) : entBefore(s1, i1, s2, i2);
        if (sw) {
          ssel[tid] = s2; ssel[ixj] = s1;
          isel[tid] = i2; isel[ixj] = i1;
        }
      }
    }
  }
  __syncthreads();
  if (tid < TOPK) {
    double bx[4];
    decode64(loc, anchors, b, isel[tid], bx);
    u.p2.box[tid][0] = bx[0]; u.p2.box[tid][1] = bx[1];
    u.p2.box[tid][2] = bx[2]; u.p2.box[tid][3] = bx[3];
    u.p2.area[tid] = (bx[2] - bx[0]) * (bx[3] - bx[1]);
  }
  __syncthreads();
  double mx1 = 0, my1 = 0, mx2 = 0, my2 = 0, mar = 0;
  if (tid < TOPK) {
    mx1 = u.p2.box[tid][0]; my1 = u.p2.box[tid][1];
    mx2 = u.p2.box[tid][2]; my2 = u.p2.box[tid][3];
    mar = u.p2.area[tid];
  }
  keepL[tid] = (tid < TOPK) && (ssel[tid] > CONF_T);
  __syncthreads();
  for (int i = 0; i < TOPK; ++i) {
    int ki = keepL[i];
    if (ki && tid > i && tid < TOPK && keepL[tid]) {
      double lx = fmax(u.p2.box[i][0], mx1);
      double ly = fmax(u.p2.box[i][1], my1);
      double rx = fmin(u.p2.box[i][2], mx2);
      double ry = fmin(u.p2.box[i][3], my2);
      double iw = rx - lx; if (iw < 0.0) iw = 0.0;
      double ih = ry - ly; if (ih < 0.0) ih = 0.0;
      double inter = iw * ih;
      double iou = inter / (u.p2.area[i] + mar - inter + 1e-12);
      if (iou > NMS_T) keepL[tid] = 0;
    }
    __syncthreads();
  }
  bool kj = (tid < TOPK) && (keepL[tid] != 0);
  unsigned long long bal = __ballot((int)kj);
  int wave = tid >> 6, lane = tid & 63;
  if (lane == 0) wmask[wave] = bal;
  __syncthreads();
  int nk = 0;
#pragma unroll
  for (int w = 0; w < 4; ++w) nk += __popcll(wmask[w]);
  if (kj) {
    int pos = 0;
    for (int w = 0; w < wave; ++w) pos += __popcll(wmask[w]);
    pos += __popcll(bal & ((1ull << lane) - 1ull));
    float* o = outbase + (size_t)pos * 5;
    o[0] = (float)ssel[tid];
    o[1] = (float)u.p2.box[tid][0];
    o[2] = (float)u.p2.box[tid][1];
    o[3] = (float)u.p2.box[tid][2];
    o[4] = (float)u.p2.box[tid][3];
  }
  if (tid < TOPK && tid >= nk) {
    float* o = outbase + (size_t)tid * 5;
    o[0] = 0.0f; o[1] = 0.0f; o[2] = 0.0f; o[3] = 0.0f; o[4] = 0.0f;
  }
}

// ---------------------------------------------------------------------------
extern "C" void kernel_launch(void* const* d_in, const int* in_sizes, int n_in,
                              void* d_out, int out_size, void* d_ws, size_t ws_size,
                              hipStream_t stream) {
  const float* loc = (const float*)d_in[0];
  const float* conf = (const float*)d_in[1];
  const float* anchors = (const float*)d_in[2];
  float* out = (float*)d_out;

  const size_t SC_BYTES = (size_t)NB * (NC - 1) * NAP * sizeof(unsigned short);  // 44.7 MB
  const size_t AUX_BYTES = (size_t)NB * NA * sizeof(double2);                    // 17.9 MB
  const size_t SH_BYTES = (size_t)NB * SHN * sizeof(unsigned);                   // 0.33 MB

  int padGrid = (NB * TOPK * 5 + 255) / 256;

  if (ws_size >= SC_BYTES + AUX_BYTES + SH_BYTES) {
    unsigned short* scores = (unsigned short*)d_ws;
    double2* aux = (double2*)((char*)d_ws + SC_BYTES);   // 16B-aligned (SC_BYTES%16==0)
    unsigned* shist = (unsigned*)((char*)d_ws + SC_BYTES + AUX_BYTES);
    k_pad<<<padGrid, 256, 0, stream>>>(scores, out, shist);
    k_prep<<<(NB * NA) / 256, 256, 0, stream>>>(conf, scores, aux, shist, 1);
    k_fast<<<NB * (NC - 1), 256, 0, stream>>>(loc, conf, anchors, scores, aux, shist, out, 1);
  } else if (ws_size >= SC_BYTES + SH_BYTES) {
    unsigned short* scores = (unsigned short*)d_ws;
    unsigned* shist = (unsigned*)((char*)d_ws + SC_BYTES);
    k_pad<<<padGrid, 256, 0, stream>>>(scores, out, shist);
    k_prep<<<(NB * NA) / 256, 256, 0, stream>>>(conf, scores, nullptr, shist, 0);
    k_fast<<<NB * (NC - 1), 256, 0, stream>>>(loc, conf, anchors, scores, nullptr, shist, out, 0);
  } else {
    k_main_nf<<<NB * NC, 256, 0, stream>>>(loc, conf, anchors, out);
  }
}

// Round 12
// 114.769 us; speedup vs baseline: 1.0434x; 1.0434x over previous
//
#include <hip/hip_runtime.h>
#include <math.h>

#pragma clang fp contract(off)

#define NB 128
#define NA 8732
#define NAP 8736          // padded u16 key row stride (16B-aligned rows)
#define NC 21
#define TOPK 200
#define BCAP 512
#define CONF_T 0.01
#define NMS_T 0.045
#define NV (NAP / 8)      // 1092 uint4 (8 u16 keys) per class row
#define HSIZE 904         // coarse buckets = u16 key codes; real x in [35,897]
#define CHN 226           // HSIZE/4 chunk sums
#define CHPAD 232         // CHN padded to multiple of 8
#define CH2N 29           // CHPAD/8 super-chunks (32 buckets each)
#define KSAMP 30          // sample order-stat (of 256) for histogram lower bound

// ---------------------------------------------------------------------------
// exact f64 masked softmax score, self-contained from conf (op order == np ref)
// (used by the tiny-ws fallback and the no-aux path)
// ---------------------------------------------------------------------------
__device__ __forceinline__ double exact_score_cf(const float* __restrict__ conf,
                                                 int b, int i, int c) {
  const float* row = conf + ((size_t)b * NA + i) * NC;
  float r[NC];
#pragma unroll
  for (int k = 0; k < NC; ++k) r[k] = row[k];
  float mx = r[0];
#pragma unroll
  for (int k = 1; k < NC; ++k) mx = fmaxf(mx, r[k]);
  double d = 0.0;
#pragma unroll
  for (int k = 0; k < NC; ++k) d += exp((double)r[k] - (double)mx);
  double s = exp((double)r[c] - (double)mx) / d;
  return (s > CONF_T) ? s : 0.0;
}

// cheap exact score via packed per-row aux {denominator, max}: one 16B load.
// bit-identical to exact_score_cf (same fmaxf chain widened exactly to f64,
// same k-ordered f64 denominator sum).
__device__ __forceinline__ double exact_score_aux(const float* __restrict__ conf,
                                                  const double2* __restrict__ aux,
                                                  int b, int i, int c) {
  size_t r = (size_t)b * NA + i;
  double v = (double)conf[r * NC + c];
  double2 a = aux[r];                 // a.x = denom, a.y = (double)mx
  double s = exp(v - a.y) / a.x;
  return (s > CONF_T) ? s : 0.0;
}

__device__ __forceinline__ double exact_score(const float* __restrict__ conf,
                                              const double2* __restrict__ aux,
                                              int use_aux, int b, int i, int c) {
  if (use_aux) return exact_score_aux(conf, aux, b, i, c);
  return exact_score_cf(conf, b, i, c);
}

// f64 decode of one box (op order == np ref)
__device__ __forceinline__ void decode64(const float* __restrict__ loc,
                                         const float* __restrict__ anchors,
                                         int b, int ai, double* o) {
  const float* lp = loc + ((size_t)b * NA + ai) * 4;
  const float* ap = anchors + (size_t)ai * 4;
  double l0 = (double)lp[0], l1 = (double)lp[1];
  double l2 = (double)lp[2], l3 = (double)lp[3];
  double a0 = (double)ap[0], a1 = (double)ap[1];
  double a2 = (double)ap[2], a3 = (double)ap[3];
  double cx = a0 + (l0 * 0.1) * a2;
  double cy = a1 + (l1 * 0.1) * a3;
  double w = a2 * exp(l2 * 0.2);
  double h = a3 * exp(l3 * 0.2);
  o[0] = cx - 0.5 * w; o[1] = cy - 0.5 * h;
  o[2] = cx + 0.5 * w; o[3] = cy + 0.5 * h;
}

__device__ __forceinline__ bool entBefore(double sa, int ia, double sb, int ib) {
  return (sa > sb) || (sa == sb && ia < ib);
}

// suffix-inclusive sum across a 64-lane wave; lanes holding no value must pass 0
__device__ __forceinline__ unsigned wave_suffix_sum(unsigned v, int lane) {
#pragma unroll
  for (int off = 1; off < 64; off <<= 1) {
    unsigned o = (unsigned)__shfl_down((int)v, off);
    v += (lane + off < 64) ? o : 0u;
  }
  return v;
}

// ---------------------------------------------------------------------------
// k_prep: u16 softmax keys (top 16 f32 bits; bucket machinery only ever uses
// bits [30:16]) + packed per-row aux {f64 denominator, f64(max)}.
// (R11's in-prep histogram reverted: k_prep is at its BW floor; added work
// there cost more than it saved in k_fast.)
// ---------------------------------------------------------------------------
__global__ __launch_bounds__(256) void k_prep(const float* __restrict__ conf,
                                              unsigned short* __restrict__ scores,
                                              double2* __restrict__ aux,
                                              int do_aux) {
  __shared__ float rows[256 * NC];
  int base = blockIdx.x * 256;                  // NB*NA == 4366*256 exactly
  const float4* src = (const float4*)(conf + (size_t)base * NC);
  float4* dst = (float4*)rows;
  for (int t = threadIdx.x; t < (256 * NC) / 4; t += 256) dst[t] = src[t];
  __syncthreads();
  int g = base + threadIdx.x;
  const float* row = rows + threadIdx.x * NC;
  float v[NC];
#pragma unroll
  for (int k = 0; k < NC; ++k) v[k] = row[k];
  float mx = v[0];
#pragma unroll
  for (int k = 1; k < NC; ++k) mx = fmaxf(mx, v[k]);
  float e[NC], s = 0.0f;
#pragma unroll
  for (int k = 0; k < NC; ++k) {
    e[k] = expf(v[k] - mx);
    s += e[k];
  }
  float inv = 1.0f / s;
  int b = g / NA, i = g - b * NA;
#pragma unroll
  for (int cc = 1; cc < NC; ++cc) {
    float sc = e[cc] * inv;
    scores[(size_t)(b * (NC - 1) + (cc - 1)) * NAP + i] =
        (sc > 0.0099f) ? (unsigned short)(__float_as_uint(sc) >> 16)
                       : (unsigned short)0;
  }
  if (do_aux) {
    double d = 0.0;
#pragma unroll
    for (int k = 0; k < NC; ++k) d += exp((double)v[k] - (double)mx);
    aux[g] = make_double2(d, (double)mx);   // coalesced 16B
  }
}

// zero the 4-entry pad of each u16 key row AND the class-0 output rows
// (k_fast does not launch c==0 blocks)
__global__ __launch_bounds__(256) void k_pad(unsigned short* __restrict__ scores,
                                             float* __restrict__ out) {
  int t = blockIdx.x * 256 + threadIdx.x;
  if (t < NB * TOPK * 5) {
    int bb = t / (TOPK * 5);
    int r = t - bb * (TOPK * 5);
    out[(size_t)bb * NC * TOPK * 5 + r] = 0.0f;
  }
  if (t < NB * (NC - 1)) {
    unsigned short* p = scores + (size_t)t * NAP + NA;
    p[0] = 0; p[1] = 0; p[2] = 0; p[3] = 0;
  }
}

// ---------------------------------------------------------------------------
// k_fast: one 256-thread block per (b,c>=1), XCD-swizzled, 8 blocks/CU.
// Streaming u16 keys (R5-proven two-pass), wave-parallel scans, sampled
// lower-bound L on histogram atomics (partial hist clear from L's chunk),
// sort-free top-K via suffix-sum direct placement, f32 output decode +
// parallel f64 decode to LDS for the exact NMS guard, lazy greedy NMS
// (kept-box area recomputed from fbox registers: one LDS read saved/iter).
// ---------------------------------------------------------------------------
__global__ __launch_bounds__(256, 8) void k_fast(const float* __restrict__ loc,
                                                 const float* __restrict__ conf,
                                                 const float* __restrict__ anchors,
                                                 const unsigned short* __restrict__ scores,
                                                 const double2* __restrict__ aux,
                                                 float* __restrict__ out,
                                                 int use_aux) {
  int id = blockIdx.x;
  int xcd = id & 7, slot0 = id >> 3;    // same-b classes share an XCD
  int c = 1 + (slot0 % (NC - 1));
  int b = (slot0 / (NC - 1)) * 8 + xcd;
  int tid = threadIdx.x;
  float* outbase = out + ((size_t)(b * NC + c)) * TOPK * 5;

  __shared__ unsigned hist[HSIZE];    // counts -> (atomicSub) cursors; radix reuses [0:256)
  __shared__ unsigned chunk[CHPAD];   // 4-bucket sums (padded with zeros)
  __shared__ unsigned chunk2[32];     // sample bins -> excl. suffix over super-chunks
  union U2 {  // boundary phase vs f64 boxes for NMS guard (disjoint in time)
    struct { double bnds[BCAP]; int bndi[BCAP]; } bb;  // 6144 B
    double dbox[TOPK][4];                              // 6400 B
  };
  __shared__ U2 u2;
  union U3 {  // selection phase vs NMS phase (disjoint in time)
    unsigned suf[HSIZE];                                   // 3616 B
    struct { float4 fbox[TOPK]; float farea[TOPK]; } fb;   // 4000 B
  };
  __shared__ U3 u3;
  __shared__ double ssel[256];
  __shared__ int isel[256];
  __shared__ unsigned keepw[7];
  __shared__ int ctl_cnt, ctl_m, ctl_n1, ctl_kneed, ctl_lo, ctl_hi, ctl_k;
  __shared__ int ctl_fix, ctl_redo;
  __shared__ unsigned ctl_pref, ctl_L;

  const unsigned short* srow =
      scores + (size_t)(b * (NC - 1) + (c - 1)) * NAP;
  const uint4* sv = (const uint4*)srow;

  // ---- P0: init + 256-key strided sample -> lower bound L ----
  for (int t = tid; t < TOPK; t += 256) isel[t] = 0;   // safety vs stale slots
  if (tid < 32) chunk2[tid] = 0u;
  if (tid == 0) { ctl_cnt = 0; ctl_m = 0; ctl_fix = 0; }
  __syncthreads();
  {
    unsigned k16 = srow[tid * 34];     // 34*255 = 8670 < NA
    if (k16) {
      int x = (int)k16 - 0x3BFF;
      if (x < 1) x = 1;
      if (x > HSIZE - 1) x = HSIZE - 1;
      atomicAdd(&chunk2[x >> 5], 1u);  // super-chunk bins [0,28]
    }
  }
  __syncthreads();
  // wave-parallel L scan: L = super-chunk edge with sample-count-above >= KSAMP
  if (tid < 64) {
    unsigned h = (tid < CH2N) ? chunk2[tid] : 0u;
    unsigned s = wave_suffix_sum(h, tid);
    unsigned long long bal = __ballot((int)(tid < CH2N && s >= (unsigned)KSAMP));
    if (tid == 0) {
      int w = bal ? (63 - (int)__clzll(bal)) : -1;
      // P(true count above L < TOPK) ~ 5e-6 per block; redo loop covers exactly.
      ctl_L = (w >= 1) ? (unsigned)(0x3BFF + (w << 5)) : 0u;
    }
  }
  __syncthreads();

  // ---- P1..P4 loop: filtered histogram -> wave-parallel D-scan ----
  unsigned L16x = ctl_L ? ctl_L : 1u;
  int lo, hi, n1, kneed;
  for (;;) {
    // partial clear: P1 only touches bins >= xL; bins in [xL&~3, xL) must be
    // zero so P2's chunk sums are exact; bins below xL's chunk are never read
    // (D-scan walks from the top; suf/band reads are >= lo >= xL-1 and the
    // band collect is a data-driven key compare).
    {
      int xL = (int)(L16x - 0x3BFFu);
      if (xL < 1) xL = 1;
      int cstart = (xL >> 2) << 2;
      for (int t = cstart + tid; t < HSIZE; t += 256) hist[t] = 0u;
    }
    if (tid == 0) ctl_redo = 0;
    __syncthreads();
    // P1: histogram keys >= L only. Invariant: nonzero keys have
    // x = key-0x3BFF in [35,897] (masked softmax in (0.0099, ~1.004]).
    for (int q = tid; q < NV; q += 256) {
      uint4 v = sv[q];
      unsigned ks[8] = {v.x & 0xFFFFu, v.x >> 16, v.y & 0xFFFFu, v.y >> 16,
                        v.z & 0xFFFFu, v.z >> 16, v.w & 0xFFFFu, v.w >> 16};
#pragma unroll
      for (int t = 0; t < 8; ++t) {
        if (ks[t] >= L16x) atomicAdd(&hist[(int)ks[t] - 0x3BFF], 1u);
      }
    }
    __syncthreads();
    // P2: chunk sums (4 buckets each), pad to CHPAD with zeros. Chunks below
    // L's chunk may read stale bins -> garbage chunk values, but those chunks
    // are never consulted by the D-scan (stops at/above D >= xL) and their
    // suf entries are never read.
    {
      int xL = (int)(L16x - 0x3BFFu);
      if (xL < 1) xL = 1;
      int cfirst = xL >> 2;
      if (tid < CHN) {
        if (tid >= cfirst) {
          unsigned csum = 0;
#pragma unroll
          for (int j = 0; j < 4; ++j) csum += hist[tid * 4 + j];
          chunk[tid] = csum;
        } else {
          chunk[tid] = 0u;   // keep super-chunk sums exact above L
        }
      } else if (tid < CHPAD) {
        chunk[tid] = 0u;
      }
    }
    __syncthreads();
    // P3+P4 fused on wave 0: super-chunk sums, suffix scans, D-scan, and
    // exclusive-suffix conversion — all via shfl/ballot.
    if (tid < 64) {
      int lane = tid;
      unsigned h2 = 0;
      if (lane < CH2N) {
        int cb = lane * 8;
#pragma unroll
        for (int j = 0; j < 8; ++j) h2 += chunk[cb + j];
      }
      unsigned s2 = wave_suffix_sum(h2, lane);
      unsigned long long bal = __ballot((int)(lane < CH2N && s2 >= (unsigned)TOPK));
      int t2 = bal ? (63 - (int)__clzll(bal)) : -1;
      if (t2 < 0 && L16x > 1u) {
        if (lane == 0) ctl_redo = 1;   // filtered total < TOPK: redo unfiltered
      } else {
        if (t2 < 0) {
          // genuinely sparse: fewer than TOPK nonzero keys (total = s2 @ lane 0)
          if (lane == 0) {
            ctl_lo = 1; ctl_hi = 0; ctl_n1 = (int)s2; ctl_kneed = TOPK - (int)s2;
          }
        } else {
          unsigned cumS = (unsigned)__shfl((int)(s2 - h2), t2);  // count(>super t2)
          unsigned hc = (lane < 8) ? chunk[t2 * 8 + lane] : 0u;
          unsigned sc = wave_suffix_sum(hc, lane);
          unsigned long long balc =
              __ballot((int)(lane < 8 && cumS + sc >= (unsigned)TOPK));
          int jc = 63 - (int)__clzll(balc);
          int tc = t2 * 8 + jc;
          unsigned cumC = cumS + (unsigned)__shfl((int)(sc - hc), jc);
          unsigned hb = (lane < 4) ? hist[tc * 4 + lane] : 0u;
          unsigned sb = wave_suffix_sum(hb, lane);
          unsigned long long balb =
              __ballot((int)(lane < 4 && cumC + sb >= (unsigned)TOPK));
          int jb = 63 - (int)__clzll(balb);
          int D = tc * 4 + jb;
          unsigned cum = cumC + (unsigned)__shfl((int)(sb - hb), jb);  // count(>D)
          int hi_ = (D + 1 < HSIZE) ? D + 1 : D;
          int lo_ = (D - 1 >= 1) ? D - 1 : D;
          unsigned hup = (hi_ > D) ? hist[hi_] : 0u;
          if (lane == 0) {
            ctl_lo = lo_; ctl_hi = hi_;
            ctl_n1 = (int)(cum - hup);        // count(buckets > hi)
            ctl_kneed = TOPK - ctl_n1;
          }
        }
        if (lane < 32) chunk2[lane] = s2 - h2;   // exclusive suffix (super level)
      }
    }
    __syncthreads();
    if (!ctl_redo) break;
    L16x = 1u;
  }
  lo = ctl_lo; hi = ctl_hi; n1 = ctl_n1; kneed = ctl_kneed;

  // ---- P5: per-bucket suffix sums: suf[x] = #keys in buckets > x. Entries
  //      below L's chunk are garbage but never read (reads at x >= lo). ----
  if (tid < CHN) {
    unsigned s = chunk2[tid >> 3];
    int ge = ((tid >> 3) + 1) << 3;
    for (int u = tid + 1; u < ge; ++u) s += chunk[u];  // padded zeros safe
    int b0 = tid * 4;
    unsigned h3 = hist[b0 + 3], h2 = hist[b0 + 2], h1 = hist[b0 + 1];
    u3.suf[b0 + 3] = s;
    u3.suf[b0 + 2] = s + h3;
    u3.suf[b0 + 1] = s + h3 + h2;
    u3.suf[b0 + 0] = s + h3 + h2 + h1;
  }
  __syncthreads();

  // ---- P7: collect (stream from L1/L2). Certain (bucket > hi): direct to
  //      final bucket span via atomicSub cursor on hist (counts exact for
  //      x > hi; no clear pass). Boundary band [lo..hi] -> bndi (data-driven
  //      key compare, so the L-filter can never lose band members). ----
  {
    unsigned tC16 = (unsigned)(0x3C00 + hi);   // key16 >= tC16 <=> bucket > hi
    unsigned tB16 = (unsigned)(0x3BFF + lo);   // key16 >= tB16 <=> bucket >= lo
    for (int q = tid; q < NV; q += 256) {
      uint4 v = sv[q];
      unsigned ks[8] = {v.x & 0xFFFFu, v.x >> 16, v.y & 0xFFFFu, v.y >> 16,
                        v.z & 0xFFFFu, v.z >> 16, v.w & 0xFFFFu, v.w >> 16};
#pragma unroll
      for (int t = 0; t < 8; ++t) {
        unsigned key = ks[t];
        if (key >= tC16) {
          int x = (int)key - 0x3BFF;
          int slot = (int)u3.suf[x] + (int)atomicSub(&hist[x], 1u) - 1;
          if (slot < TOPK) isel[slot] = (x << 16) | (q * 8 + t);  // packed
        } else if (key >= tB16) {
          int p = atomicAdd(&ctl_m, 1);
          if (p < BCAP) u2.bb.bndi[p] = q * 8 + t;
        }
      }
    }
  }
  __syncthreads();
  int m = (hi > 0) ? ctl_m : 0;

  if (hi > 0 && m > BCAP) {
    // ---- overflow fallback: exact 2-pass u16 radix + full bitonic (~never) ----
    if (tid == 0) { ctl_k = TOPK; ctl_pref = 0u; }
    __syncthreads();
    for (int shift = 8; shift >= 0; shift -= 8) {
      hist[tid] = 0u;
      __syncthreads();
      unsigned pref = ctl_pref;
      for (int q = tid; q < NV; q += 256) {
        uint4 v = sv[q];
        unsigned ks[8] = {v.x & 0xFFFFu, v.x >> 16, v.y & 0xFFFFu, v.y >> 16,
                          v.z & 0xFFFFu, v.z >> 16, v.w & 0xFFFFu, v.w >> 16};
#pragma unroll
        for (int t = 0; t < 8; ++t) {
          unsigned key = ks[t];
          if (key == 0u) continue;
          bool match = (shift == 8) || ((key >> 8) == (pref >> 8));
          if (match) atomicAdd(&hist[(key >> shift) & 255u], 1u);
        }
      }
      __syncthreads();
      if (tid == 0) {
        int k = ctl_k;
        unsigned cum = 0;
        int d = 255;
        for (; d > 0; --d) {
          unsigned h = hist[d];
          if (cum + h >= (unsigned)k) break;
          cum += h;
        }
        ctl_k = k - (int)cum;
        ctl_pref = pref | ((unsigned)d << shift);
      }
      __syncthreads();
    }
    unsigned Tf = ctl_pref;
    kneed = ctl_k;
    n1 = TOPK - kneed;
    if (tid == 0) { ctl_cnt = 0; ctl_m = 0; }
    __syncthreads();
    for (int q = tid; q < NV; q += 256) {
      uint4 v = sv[q];
      unsigned ks[8] = {v.x & 0xFFFFu, v.x >> 16, v.y & 0xFFFFu, v.y >> 16,
                        v.z & 0xFFFFu, v.z >> 16, v.w & 0xFFFFu, v.w >> 16};
#pragma unroll
      for (int t = 0; t < 8; ++t) {
        unsigned key = ks[t];
        if (key > Tf) {
          int p = atomicAdd(&ctl_cnt, 1);
          if (p < 256) isel[p] = q * 8 + t;   // raw idx
        } else if (key == Tf) {
          int p = atomicAdd(&ctl_m, 1);
          if (p < BCAP) u2.bb.bndi[p] = q * 8 + t;
        }
      }
    }
    __syncthreads();
    m = ctl_m;
    if (m > BCAP) m = BCAP;
    for (int q = tid; q < m; q += 256)
      u2.bb.bnds[q] = exact_score(conf, aux, use_aux, b, u2.bb.bndi[q], c);
    __syncthreads();
    for (int q = tid; q < m; q += 256) {
      double sq = u2.bb.bnds[q];
      int iq = u2.bb.bndi[q];
      int rank = 0;
      for (int r = 0; r < m; ++r)
        if (entBefore(u2.bb.bnds[r], u2.bb.bndi[r], sq, iq)) ++rank;
      if (rank < kneed) { isel[n1 + rank] = iq; ssel[n1 + rank] = sq; }
    }
    __syncthreads();
    if (tid < TOPK) {
      if (tid < n1) ssel[tid] = exact_score(conf, aux, use_aux, b, isel[tid], c);
    } else {
      ssel[tid] = -1.0;
      isel[tid] = 0x7fffffff;
    }
    // bitonic sort 256: (score desc, index asc)
    for (int kk = 2; kk <= 256; kk <<= 1) {
      for (int j = kk >> 1; j > 0; j >>= 1) {
        __syncthreads();
        int ixj = tid ^ j;
        if (ixj > tid) {
          double s1 = ssel[tid], s2 = ssel[ixj];
          int i1 = isel[tid], i2 = isel[ixj];
          bool up = ((tid & kk) == 0);
          bool sw = up ? entBefore(s2, i2, s1, i1) : entBefore(s1, i1, s2, i2);
          if (sw) {
            ssel[tid] = s2; ssel[ixj] = s1;
            isel[tid] = i2; isel[ixj] = i1;
          }
        }
      }
    }
    __syncthreads();
  } else {
    // ---- main path: sort-free ranking ----
    // P8a: exact scores. certain at temp slot tid (<n1); boundary into bnds.
    if (tid < n1)
      ssel[tid] = exact_score(conf, aux, use_aux, b, isel[tid] & 0xFFFF, c);
    if (hi > 0) {
      for (int q = tid; q < m; q += 256)
        u2.bb.bnds[q] = exact_score(conf, aux, use_aux, b, u2.bb.bndi[q], c);
    }
    __syncthreads();
    // P8b: ranks. Certain: within-bucket exact rank (reads ssel/isel [0,n1)).
    //      Boundary: exact rank among m, writes [n1,200) (disjoint region).
    double myS = 0.0;
    int myI = 0, myPos = -1;
    if (tid < n1) {
      int packed = isel[tid];
      int bk = packed >> 16;
      myI = packed & 0xFFFF;
      myS = ssel[tid];
      int base = (int)u3.suf[bk];
      int len = (int)u3.suf[bk - 1] - base;
      int r = 0;
      for (int u = base; u < base + len; ++u) {
        if (u == tid) continue;
        double ps = ssel[u];
        int pI = isel[u] & 0xFFFF;
        if (entBefore(ps, pI, myS, myI)) ++r;
      }
      myPos = base + r;
    }
    if (hi > 0) {
      for (int q = tid; q < m; q += 256) {
        double sq = u2.bb.bnds[q];
        int iq = u2.bb.bndi[q];
        int rank = 0;
        for (int r = 0; r < m; ++r)
          if (entBefore(u2.bb.bnds[r], u2.bb.bndi[r], sq, iq)) ++rank;
        if (rank < kneed) { isel[n1 + rank] = iq; ssel[n1 + rank] = sq; }
      }
    } else {
      // sparse: zero-score dummies (keep=false downstream -> zero rows)
      for (int j = n1 + tid; j < TOPK; j += 256) {
        isel[j] = j - n1;
        ssel[j] = 0.0;
      }
    }
    __syncthreads();
    // P8c: certain final placement (exact within-bucket order)
    if (myPos >= 0 && myPos < TOPK) { ssel[myPos] = myS; isel[myPos] = myI; }
    __syncthreads();
    // P8d: exact-order guard. Inversions possible only for exact scores within
    // key error (~4e-6 rel) of a bucket edge; detect and (rarely) fix.
    if (tid < 64) {
      bool inv = false;
      for (int j = tid + 1; j < TOPK; j += 64)
        if (entBefore(ssel[j], isel[j], ssel[j - 1], isel[j - 1])) inv = true;
      unsigned long long bal = __ballot((int)inv);
      if (tid == 0 && bal != 0ull) ctl_fix = 1;
    }
    __syncthreads();
    if (ctl_fix) {
      if (tid == 0) {
        for (int a = 1; a < TOPK; ++a) {
          double s = ssel[a];
          int ii = isel[a];
          int p = a - 1;
          while (p >= 0 && entBefore(s, ii, ssel[p], isel[p])) {
            ssel[p + 1] = ssel[p]; isel[p + 1] = isel[p]; --p;
          }
          ssel[p + 1] = s; isel[p + 1] = ii;
        }
      }
      __syncthreads();
    }
  }

  // ---- decode own box: f32 for output/tier-1 (HW expf; matches f32
  //      reference op order -> absmax 0) AND parallel f64 to LDS dbox for
  //      the exact NMS guard (R5/R10-proven: guard = 8 LDS reads). ----
  float fx1 = 0, fy1 = 0, fx2 = 0, fy2 = 0;
  if (tid < TOPK) {
    int ai = isel[tid];
    const float* lp = loc + ((size_t)b * NA + ai) * 4;
    const float* ap = anchors + (size_t)ai * 4;
    float l0 = lp[0], l1 = lp[1], l2 = lp[2], l3 = lp[3];
    float a0 = ap[0], a1 = ap[1], a2 = ap[2], a3 = ap[3];
    float cx = a0 + (l0 * 0.1f) * a2;
    float cy = a1 + (l1 * 0.1f) * a3;
    float w = a2 * expf(l2 * 0.2f);
    float h = a3 * expf(l3 * 0.2f);
    fx1 = cx - 0.5f * w; fy1 = cy - 0.5f * h;
    fx2 = cx + 0.5f * w; fy2 = cy + 0.5f * h;
    u3.fb.fbox[tid] = make_float4(fx1, fy1, fx2, fy2);
    u3.fb.farea[tid] = (fx2 - fx1) * (fy2 - fy1);
    // f64 decode (reuses loaded lp/ap; software exps run in parallel
    // across 200 threads, once per block)
    double dcx = (double)a0 + ((double)l0 * 0.1) * (double)a2;
    double dcy = (double)a1 + ((double)l1 * 0.1) * (double)a3;
    double dw = (double)a2 * exp((double)l2 * 0.2);
    double dh = (double)a3 * exp((double)l3 * 0.2);
    u2.dbox[tid][0] = dcx - 0.5 * dw;
    u2.dbox[tid][1] = dcy - 0.5 * dh;
    u2.dbox[tid][2] = dcx + 0.5 * dw;
    u2.dbox[tid][3] = dcy + 0.5 * dh;
  }
  __syncthreads();

  // ---- lazy greedy NMS on wave 0: alive-mask ballots, jump to next kept
  //      row, IoU on the fly. Kept-box area recomputed from fbox registers
  //      (same f32 expression on same values as farea -> bit-identical;
  //      saves one dependent LDS read per serial iteration). f32
  //      mult-compare; tight cases decided in exact f64 from LDS dbox. ----
  if (tid < 64) {
    int l = tid;
    unsigned kr = 0u;
    float4 ob[4]; float oa[4];
#pragma unroll
    for (int q = 0; q < 4; ++q) {
      int j = l + 64 * q;
      if (j < TOPK) {
        if (ssel[j] > CONF_T) kr |= 1u << q;
        ob[q] = u3.fb.fbox[j];
        oa[q] = u3.fb.farea[j];
      } else {
        ob[q] = make_float4(0.0f, 0.0f, 0.0f, 0.0f);
        oa[q] = 0.0f;
      }
    }
    int cur = 0;
    while (cur < TOPK) {
      unsigned long long ms0 = __ballot((int)(kr & 1u));
      unsigned long long ms1 = __ballot((int)(kr & 2u));
      unsigned long long ms2 = __ballot((int)(kr & 4u));
      unsigned long long ms3 = __ballot((int)(kr & 8u));
      int q0 = cur >> 6;
      int sh = cur & 63;
      unsigned long long below = sh ? ((1ull << sh) - 1ull) : 0ull;
      unsigned long long t0 = (q0 == 0) ? (ms0 & ~below) : 0ull;
      unsigned long long t1 = (q0 < 1) ? ms1 : ((q0 == 1) ? (ms1 & ~below) : 0ull);
      unsigned long long t2 = (q0 < 2) ? ms2 : ((q0 == 2) ? (ms2 & ~below) : 0ull);
      unsigned long long t3 = (q0 < 3) ? ms3 : (ms3 & ~below);
      int i = TOPK;
      if (t0) i = __ffsll(t0) - 1;
      else if (t1) i = 64 + __ffsll(t1) - 1;
      else if (t2) i = 128 + __ffsll(t2) - 1;
      else if (t3) i = 192 + __ffsll(t3) - 1;
      if (i >= TOPK) break;          // no alive row left
      float4 fbi = u3.fb.fbox[i];    // LDS broadcast (single b128 read)
      float fai = (fbi.z - fbi.x) * (fbi.w - fbi.y);   // == farea[i] bitwise
#pragma unroll
      for (int q = 0; q < 4; ++q) {
        int r = l + 64 * q;
        if (r > i && r < TOPK && ((kr >> q) & 1u)) {
          float lx = fmaxf(fbi.x, ob[q].x), ly = fmaxf(fbi.y, ob[q].y);
          float rx = fminf(fbi.z, ob[q].z), ry = fminf(fbi.w, ob[q].w);
          float iw = fmaxf(rx - lx, 0.0f), ih = fmaxf(ry - ly, 0.0f);
          float inter = iw * ih;
          float uni = fai + oa[q] - inter + 1e-12f;
          float diff = inter - 0.045f * uni;    // sign(diff) == sign(io-T)
          bool sup;
          if (fabsf(diff) < 3e-4f * uni) {      // |io-T| < 3e-4: decide in f64
            double ix1 = u2.dbox[i][0], iy1 = u2.dbox[i][1];
            double ix2 = u2.dbox[i][2], iy2 = u2.dbox[i][3];
            double jx1 = u2.dbox[r][0], jy1 = u2.dbox[r][1];
            double jx2 = u2.dbox[r][2], jy2 = u2.dbox[r][3];
            double dlx = fmax(ix1, jx1), dly = fmax(iy1, jy1);
            double drx = fmin(ix2, jx2), dry = fmin(iy2, jy2);
            double diw = drx - dlx; if (diw < 0.0) diw = 0.0;
            double dih = dry - dly; if (dih < 0.0) dih = 0.0;
            double dint = diw * dih;
            double dai = (ix2 - ix1) * (iy2 - iy1);
            double daj = (jx2 - jx1) * (jy2 - jy1);
            sup = dint > NMS_T * (dai + daj - dint + 1e-12);
          } else {
            sup = diff > 0.0f;
          }
          if (sup) kr &= ~(1u << q);
        }
      }
      cur = i + 1;
    }
#pragma unroll
    for (int q = 0; q < 4; ++q) {
      unsigned long long bal = __ballot((int)((kr >> q) & 1u));
      if (l == 0) {
        keepw[2 * q] = (unsigned)bal;
        if (2 * q + 1 < 7) keepw[2 * q + 1] = (unsigned)(bal >> 32);
      }
    }
  }
  __syncthreads();

  // ---- pack kept rows to the front, zero-fill the rest ----
  int nk = 0;
#pragma unroll
  for (int w = 0; w < 7; ++w) nk += __popc(keepw[w]);
  if (tid < TOPK) {
    int j = tid;
    bool kept = (keepw[j >> 5] >> (j & 31)) & 1u;
    if (kept) {
      int pos = 0;
      for (int w = 0; w < (j >> 5); ++w) pos += __popc(keepw[w]);
      pos += __popc(keepw[j >> 5] & ((1u << (j & 31)) - 1u));
      float* o = outbase + (size_t)pos * 5;
      o[0] = (float)ssel[j];
      o[1] = fx1;
      o[2] = fy1;
      o[3] = fx2;
      o[4] = fy2;
    }
    if (j >= nk) {
      float* o = outbase + (size_t)j * 5;
      o[0] = 0.0f; o[1] = 0.0f; o[2] = 0.0f; o[3] = 0.0f; o[4] = 0.0f;
    }
  }
}

// ===========================================================================
// Tiny-workspace fallback (R2-proven, self-contained) — only if ws too small
// ===========================================================================
__global__ __launch_bounds__(256) void k_main_nf(const float* __restrict__ loc,
                                                 const float* __restrict__ conf,
                                                 const float* __restrict__ anchors,
                                                 float* __restrict__ out) {
  int bc = blockIdx.x;
  int b = bc / NC;
  int c = bc % NC;
  int tid = threadIdx.x;
  float* outbase = out + (size_t)bc * TOPK * 5;
  if (c == 0) {
    for (int k = tid; k < TOPK * 5; k += 256) outbase[k] = 0.0f;
    return;
  }
  union U {
    float sf[NA];
    struct { double box[TOPK][4]; double area[TOPK]; } p2;
  };
  __shared__ U u;
  __shared__ double ssel[256];
  __shared__ int isel[256];
  __shared__ unsigned hist[256];
  __shared__ double bnds[256];
  __shared__ int bndi[256];
  __shared__ int keepL[256];
  __shared__ unsigned long long wmask[4];
  __shared__ int ctl_k, ctl_cnt, ctl_m;
  __shared__ unsigned ctl_pref;

  for (int i = tid; i < NA; i += 256)
    u.sf[i] = (float)exact_score_cf(conf, b, i, c);
  if (tid == 0) { ctl_k = TOPK; ctl_pref = 0u; }
  __syncthreads();
  for (int shift = 24; shift >= 0; shift -= 8) {
    hist[tid] = 0u;
    __syncthreads();
    unsigned pref = ctl_pref;
    for (int i = tid; i < NA; i += 256) {
      unsigned key = __float_as_uint(u.sf[i]);
      bool match = (shift == 24) || ((key >> (shift + 8)) == (pref >> (shift + 8)));
      if (match) atomicAdd(&hist[(key >> shift) & 255u], 1u);
    }
    __syncthreads();
    if (tid == 0) {
      int k = ctl_k;
      unsigned cum = 0;
      int d = 255;
      for (; d > 0; --d) {
        unsigned h = hist[d];
        if (cum + h >= (unsigned)k) break;
        cum += h;
      }
      ctl_k = k - (int)cum;
      ctl_pref = pref | ((unsigned)d << shift);
    }
    __syncthreads();
  }
  unsigned Tf = ctl_pref;
  int kneed = ctl_k;
  int n1 = TOPK - kneed;
  if (tid == 0) { ctl_cnt = 0; ctl_m = 0; }
  __syncthreads();
  for (int i = tid; i < NA; i += 256) {
    unsigned key = __float_as_uint(u.sf[i]);
    if (key > Tf) {
      int p = atomicAdd(&ctl_cnt, 1);
      if (p < 256) isel[p] = i;
    } else if (key == Tf && Tf != 0u) {
      int q = atomicAdd(&ctl_m, 1);
      if (q < 256) bndi[q] = i;
    }
  }
  __syncthreads();
  int zf;
  if (Tf == 0u) {
    zf = n1;
    for (int j = n1 + tid; j < TOPK; j += 256) isel[j] = j - n1;
  } else {
    zf = TOPK;
    int m = ctl_m;
    if (m > 256) m = 256;
    if (tid < m) bnds[tid] = exact_score_cf(conf, b, bndi[tid], c);
    __syncthreads();
    if (tid < m) {
      double sq = bnds[tid];
      int iq = bndi[tid];
      int rank = 0;
      for (int r = 0; r < m; ++r)
        if (entBefore(bnds[r], bndi[r], sq, iq)) ++rank;
      if (rank < kneed) isel[n1 + rank] = iq;
    }
  }
  __syncthreads();
  if (tid < TOPK) {
    ssel[tid] = (tid < zf) ? exact_score_cf(conf, b, isel[tid], c) : 0.0;
  } else {
    ssel[tid] = -1.0;
    isel[tid] = 0x7fffffff;
  }
  for (int kk = 2; kk <= 256; kk <<= 1) {
    for (int j = kk >> 1; j > 0; j >>= 1) {
      __syncthreads();
      int ixj = tid ^ j;
      if (ixj > tid) {
        double s1 = ssel[tid], s2 = ssel[ixj];
        int i1 = isel[tid], i2 = isel[ixj];
        bool up = ((tid & kk) == 0);
        bool sw = up ? entBefore(s2, i2, s1, i1) : entBefore(s1, i1, s2, i2);
        if (sw) {
          ssel[tid] = s2; ssel[ixj] = s1;
          isel[tid] = i2; isel[ixj] = i1;
        }
      }
    }
  }
  __syncthreads();
  if (tid < TOPK) {
    double bx[4];
    decode64(loc, anchors, b, isel[tid], bx);
    u.p2.box[tid][0] = bx[0]; u.p2.box[tid][1] = bx[1];
    u.p2.box[tid][2] = bx[2]; u.p2.box[tid][3] = bx[3];
    u.p2.area[tid] = (bx[2] - bx[0]) * (bx[3] - bx[1]);
  }
  __syncthreads();
  double mx1 = 0, my1 = 0, mx2 = 0, my2 = 0, mar = 0;
  if (tid < TOPK) {
    mx1 = u.p2.box[tid][0]; my1 = u.p2.box[tid][1];
    mx2 = u.p2.box[tid][2]; my2 = u.p2.box[tid][3];
    mar = u.p2.area[tid];
  }
  keepL[tid] = (tid < TOPK) && (ssel[tid] > CONF_T);
  __syncthreads();
  for (int i = 0; i < TOPK; ++i) {
    int ki = keepL[i];
    if (ki && tid > i && tid < TOPK && keepL[tid]) {
      double lx = fmax(u.p2.box[i][0], mx1);
      double ly = fmax(u.p2.box[i][1], my1);
      double rx = fmin(u.p2.box[i][2], mx2);
      double ry = fmin(u.p2.box[i][3], my2);
      double iw = rx - lx; if (iw < 0.0) iw = 0.0;
      double ih = ry - ly; if (ih < 0.0) ih = 0.0;
      double inter = iw * ih;
      double iou = inter / (u.p2.area[i] + mar - inter + 1e-12);
      if (iou > NMS_T) keepL[tid] = 0;
    }
    __syncthreads();
  }
  bool kj = (tid < TOPK) && (keepL[tid] != 0);
  unsigned long long bal = __ballot((int)kj);
  int wave = tid >> 6, lane = tid & 63;
  if (lane == 0) wmask[wave] = bal;
  __syncthreads();
  int nk = 0;
#pragma unroll
  for (int w = 0; w < 4; ++w) nk += __popcll(wmask[w]);
  if (kj) {
    int pos = 0;
    for (int w = 0; w < wave; ++w) pos += __popcll(wmask[w]);
    pos += __popcll(bal & ((1ull << lane) - 1ull));
    float* o = outbase + (size_t)pos * 5;
    o[0] = (float)ssel[tid];
    o[1] = (float)u.p2.box[tid][0];
    o[2] = (float)u.p2.box[tid][1];
    o[3] = (float)u.p2.box[tid][2];
    o[4] = (float)u.p2.box[tid][3];
  }
  if (tid < TOPK && tid >= nk) {
    float* o = outbase + (size_t)tid * 5;
    o[0] = 0.0f; o[1] = 0.0f; o[2] = 0.0f; o[3] = 0.0f; o[4] = 0.0f;
  }
}

// ---------------------------------------------------------------------------
extern "C" void kernel_launch(void* const* d_in, const int* in_sizes, int n_in,
                              void* d_out, int out_size, void* d_ws, size_t ws_size,
                              hipStream_t stream) {
  const float* loc = (const float*)d_in[0];
  const float* conf = (const float*)d_in[1];
  const float* anchors = (const float*)d_in[2];
  float* out = (float*)d_out;

  const size_t SC_BYTES = (size_t)NB * (NC - 1) * NAP * sizeof(unsigned short);  // 44.7 MB
  const size_t AUX_BYTES = (size_t)NB * NA * sizeof(double2);                    // 17.9 MB

  int padGrid = (NB * TOPK * 5 + 255) / 256;

  if (ws_size >= SC_BYTES + AUX_BYTES) {
    unsigned short* scores = (unsigned short*)d_ws;
    double2* aux = (double2*)((char*)d_ws + SC_BYTES);   // 16B-aligned (SC_BYTES%16==0)
    k_pad<<<padGrid, 256, 0, stream>>>(scores, out);
    k_prep<<<(NB * NA) / 256, 256, 0, stream>>>(conf, scores, aux, 1);
    k_fast<<<NB * (NC - 1), 256, 0, stream>>>(loc, conf, anchors, scores, aux, out, 1);
  } else if (ws_size >= SC_BYTES) {
    unsigned short* scores = (unsigned short*)d_ws;
    k_pad<<<padGrid, 256, 0, stream>>>(scores, out);
    k_prep<<<(NB * NA) / 256, 256, 0, stream>>>(conf, scores, nullptr, 0);
    k_fast<<<NB * (NC - 1), 256, 0, stream>>>(loc, conf, anchors, scores, nullptr, out, 0);
  } else {
    k_main_nf<<<NB * NC, 256, 0, stream>>>(loc, conf, anchors, out);
  }
}

// Round 13
// 110.042 us; speedup vs baseline: 1.0883x; 1.0430x over previous
//
#include <hip/hip_runtime.h>
#include <math.h>

#pragma clang fp contract(off)

#define NB 128
#define NA 8732
#define NAP 8736          // padded u16 key row stride (16B-aligned rows)
#define NC 21
#define TOPK 200
#define BCAP 512
#define CONF_T 0.01
#define NMS_T 0.045
#define NV (NAP / 8)      // 1092 uint4 (8 u16 keys) per class row
#define HSIZE 904         // coarse buckets = u16 key codes; real x in [35,897]
#define CHN 226           // HSIZE/4 chunk sums
#define CHPAD 232         // CHN padded to multiple of 8
#define CH2N 29           // CHPAD/8 super-chunks (32 buckets each)
#define KSAMP 30          // sample order-stat (of 256) for histogram lower bound

// ---------------------------------------------------------------------------
// exact f64 masked softmax score, self-contained from conf (op order == np ref)
// (used by the tiny-ws fallback and the no-aux path)
// ---------------------------------------------------------------------------
__device__ __forceinline__ double exact_score_cf(const float* __restrict__ conf,
                                                 int b, int i, int c) {
  const float* row = conf + ((size_t)b * NA + i) * NC;
  float r[NC];
#pragma unroll
  for (int k = 0; k < NC; ++k) r[k] = row[k];
  float mx = r[0];
#pragma unroll
  for (int k = 1; k < NC; ++k) mx = fmaxf(mx, r[k]);
  double d = 0.0;
#pragma unroll
  for (int k = 0; k < NC; ++k) d += exp((double)r[k] - (double)mx);
  double s = exp((double)r[c] - (double)mx) / d;
  return (s > CONF_T) ? s : 0.0;
}

// cheap exact score via packed per-row aux {denominator, max}: one 16B load.
// bit-identical to exact_score_cf (same fmaxf chain widened exactly to f64,
// same k-ordered f64 denominator sum).
__device__ __forceinline__ double exact_score_aux(const float* __restrict__ conf,
                                                  const double2* __restrict__ aux,
                                                  int b, int i, int c) {
  size_t r = (size_t)b * NA + i;
  double v = (double)conf[r * NC + c];
  double2 a = aux[r];                 // a.x = denom, a.y = (double)mx
  double s = exp(v - a.y) / a.x;
  return (s > CONF_T) ? s : 0.0;
}

__device__ __forceinline__ double exact_score(const float* __restrict__ conf,
                                              const double2* __restrict__ aux,
                                              int use_aux, int b, int i, int c) {
  if (use_aux) return exact_score_aux(conf, aux, b, i, c);
  return exact_score_cf(conf, b, i, c);
}

// f64 decode of one box (op order == np ref)
__device__ __forceinline__ void decode64(const float* __restrict__ loc,
                                         const float* __restrict__ anchors,
                                         int b, int ai, double* o) {
  const float* lp = loc + ((size_t)b * NA + ai) * 4;
  const float* ap = anchors + (size_t)ai * 4;
  double l0 = (double)lp[0], l1 = (double)lp[1];
  double l2 = (double)lp[2], l3 = (double)lp[3];
  double a0 = (double)ap[0], a1 = (double)ap[1];
  double a2 = (double)ap[2], a3 = (double)ap[3];
  double cx = a0 + (l0 * 0.1) * a2;
  double cy = a1 + (l1 * 0.1) * a3;
  double w = a2 * exp(l2 * 0.2);
  double h = a3 * exp(l3 * 0.2);
  o[0] = cx - 0.5 * w; o[1] = cy - 0.5 * h;
  o[2] = cx + 0.5 * w; o[3] = cy + 0.5 * h;
}

__device__ __forceinline__ bool entBefore(double sa, int ia, double sb, int ib) {
  return (sa > sb) || (sa == sb && ia < ib);
}

// suffix-inclusive sum across a 64-lane wave; lanes holding no value must pass 0
__device__ __forceinline__ unsigned wave_suffix_sum(unsigned v, int lane) {
#pragma unroll
  for (int off = 1; off < 64; off <<= 1) {
    unsigned o = (unsigned)__shfl_down((int)v, off);
    v += (lane + off < 64) ? o : 0u;
  }
  return v;
}

// ---------------------------------------------------------------------------
// k_prep: u16 softmax keys (top 16 f32 bits; bucket machinery only ever uses
// bits [30:16]) + packed per-row aux {f64 denominator, f64(max)}.
// Also absorbs the former k_pad: zeroes class-0 output rows and the 4-entry
// key-row pads (disjoint from k_prep's own writes; out is only read/written
// later by k_fast) -- saves one kernel dispatch.
// ---------------------------------------------------------------------------
__global__ __launch_bounds__(256) void k_prep(const float* __restrict__ conf,
                                              unsigned short* __restrict__ scores,
                                              double2* __restrict__ aux,
                                              float* __restrict__ out,
                                              int do_aux) {
  __shared__ float rows[256 * NC];
  int base = blockIdx.x * 256;                  // NB*NA == 4366*256 exactly
  const float4* src = (const float4*)(conf + (size_t)base * NC);
  float4* dst = (float4*)rows;
  for (int t = threadIdx.x; t < (256 * NC) / 4; t += 256) dst[t] = src[t];
  // merged k_pad work (fully parallel, no sync needed):
  {
    int t = base + threadIdx.x;
    if (t < NB * TOPK * 5) {
      int bb = t / (TOPK * 5);
      int r = t - bb * (TOPK * 5);
      out[(size_t)bb * NC * TOPK * 5 + r] = 0.0f;   // class-0 rows
    }
    if (t < NB * (NC - 1)) {
      unsigned short* p = scores + (size_t)t * NAP + NA;
      p[0] = 0; p[1] = 0; p[2] = 0; p[3] = 0;       // key-row pads
    }
  }
  __syncthreads();
  int g = base + threadIdx.x;
  const float* row = rows + threadIdx.x * NC;
  float v[NC];
#pragma unroll
  for (int k = 0; k < NC; ++k) v[k] = row[k];
  float mx = v[0];
#pragma unroll
  for (int k = 1; k < NC; ++k) mx = fmaxf(mx, v[k]);
  float e[NC], s = 0.0f;
#pragma unroll
  for (int k = 0; k < NC; ++k) {
    e[k] = expf(v[k] - mx);
    s += e[k];
  }
  float inv = 1.0f / s;
  int b = g / NA, i = g - b * NA;
#pragma unroll
  for (int cc = 1; cc < NC; ++cc) {
    float sc = e[cc] * inv;
    scores[(size_t)(b * (NC - 1) + (cc - 1)) * NAP + i] =
        (sc > 0.0099f) ? (unsigned short)(__float_as_uint(sc) >> 16)
                       : (unsigned short)0;
  }
  if (do_aux) {
    double d = 0.0;
#pragma unroll
    for (int k = 0; k < NC; ++k) d += exp((double)v[k] - (double)mx);
    aux[g] = make_double2(d, (double)mx);   // coalesced 16B
  }
}

// ---------------------------------------------------------------------------
// k_fast: one 256-thread block per (b,c>=1), XCD-swizzled, 8 blocks/CU.
// Streaming u16 keys (R5-proven two-pass), wave-parallel scans, sampled
// lower-bound L on histogram atomics (partial hist clear from L's chunk),
// sort-free top-K via suffix-sum direct placement, f32 output decode +
// parallel f64 decode to LDS for the exact NMS guard, lazy greedy NMS.
// ---------------------------------------------------------------------------
__global__ __launch_bounds__(256, 8) void k_fast(const float* __restrict__ loc,
                                                 const float* __restrict__ conf,
                                                 const float* __restrict__ anchors,
                                                 const unsigned short* __restrict__ scores,
                                                 const double2* __restrict__ aux,
                                                 float* __restrict__ out,
                                                 int use_aux) {
  int id = blockIdx.x;
  int xcd = id & 7, slot0 = id >> 3;    // same-b classes share an XCD
  int c = 1 + (slot0 % (NC - 1));
  int b = (slot0 / (NC - 1)) * 8 + xcd;
  int tid = threadIdx.x;
  float* outbase = out + ((size_t)(b * NC + c)) * TOPK * 5;

  __shared__ unsigned hist[HSIZE];    // counts -> (atomicSub) cursors; radix reuses [0:256)
  __shared__ unsigned chunk[CHPAD];   // 4-bucket sums (padded with zeros)
  __shared__ unsigned chunk2[32];     // sample bins -> excl. suffix over super-chunks
  union U2 {  // boundary phase vs f64 boxes for NMS guard (disjoint in time)
    struct { double bnds[BCAP]; int bndi[BCAP]; } bb;  // 6144 B
    double dbox[TOPK][4];                              // 6400 B
  };
  __shared__ U2 u2;
  union U3 {  // selection phase vs NMS phase (disjoint in time)
    unsigned suf[HSIZE];                                   // 3616 B
    struct { float4 fbox[TOPK]; float farea[TOPK]; } fb;   // 4000 B
  };
  __shared__ U3 u3;
  __shared__ double ssel[256];
  __shared__ int isel[256];
  __shared__ unsigned keepw[7];
  __shared__ int ctl_cnt, ctl_m, ctl_n1, ctl_kneed, ctl_lo, ctl_hi, ctl_k;
  __shared__ int ctl_fix, ctl_redo;
  __shared__ unsigned ctl_pref, ctl_L;

  const unsigned short* srow =
      scores + (size_t)(b * (NC - 1) + (c - 1)) * NAP;
  const uint4* sv = (const uint4*)srow;

  // ---- P0: init + 256-key strided sample -> lower bound L ----
  for (int t = tid; t < TOPK; t += 256) isel[t] = 0;   // safety vs stale slots
  if (tid < 32) chunk2[tid] = 0u;
  if (tid == 0) { ctl_cnt = 0; ctl_m = 0; ctl_fix = 0; }
  __syncthreads();
  {
    unsigned k16 = srow[tid * 34];     // 34*255 = 8670 < NA
    if (k16) {
      int x = (int)k16 - 0x3BFF;
      if (x < 1) x = 1;
      if (x > HSIZE - 1) x = HSIZE - 1;
      atomicAdd(&chunk2[x >> 5], 1u);  // super-chunk bins [0,28]
    }
  }
  __syncthreads();
  // wave-parallel L scan: L = super-chunk edge with sample-count-above >= KSAMP
  if (tid < 64) {
    unsigned h = (tid < CH2N) ? chunk2[tid] : 0u;
    unsigned s = wave_suffix_sum(h, tid);
    unsigned long long bal = __ballot((int)(tid < CH2N && s >= (unsigned)KSAMP));
    if (tid == 0) {
      int w = bal ? (63 - (int)__clzll(bal)) : -1;
      // P(true count above L < TOPK) ~ 5e-6 per block; redo loop covers exactly.
      ctl_L = (w >= 1) ? (unsigned)(0x3BFF + (w << 5)) : 0u;
    }
  }
  __syncthreads();

  // ---- P1..P4 loop: filtered histogram -> wave-parallel D-scan ----
  unsigned L16x = ctl_L ? ctl_L : 1u;
  int lo, hi, n1, kneed;
  for (;;) {
    // partial clear: P1 only touches bins >= xL; bins in [xL&~3, xL) must be
    // zero so P2's chunk sums are exact; bins below xL's chunk are never read.
    {
      int xL = (int)(L16x - 0x3BFFu);
      if (xL < 1) xL = 1;
      int cstart = (xL >> 2) << 2;
      for (int t = cstart + tid; t < HSIZE; t += 256) hist[t] = 0u;
    }
    if (tid == 0) ctl_redo = 0;
    __syncthreads();
    // P1: histogram keys >= L only. Invariant: nonzero keys have
    // x = key-0x3BFF in [35,897] (masked softmax in (0.0099, ~1.004]).
    for (int q = tid; q < NV; q += 256) {
      uint4 v = sv[q];
      unsigned ks[8] = {v.x & 0xFFFFu, v.x >> 16, v.y & 0xFFFFu, v.y >> 16,
                        v.z & 0xFFFFu, v.z >> 16, v.w & 0xFFFFu, v.w >> 16};
#pragma unroll
      for (int t = 0; t < 8; ++t) {
        if (ks[t] >= L16x) atomicAdd(&hist[(int)ks[t] - 0x3BFF], 1u);
      }
    }
    __syncthreads();
    // P2: chunk sums (4 buckets each), pad to CHPAD with zeros. Chunks below
    // L's chunk are forced to zero so super-chunk sums above L stay exact.
    {
      int xL = (int)(L16x - 0x3BFFu);
      if (xL < 1) xL = 1;
      int cfirst = xL >> 2;
      if (tid < CHN) {
        if (tid >= cfirst) {
          unsigned csum = 0;
#pragma unroll
          for (int j = 0; j < 4; ++j) csum += hist[tid * 4 + j];
          chunk[tid] = csum;
        } else {
          chunk[tid] = 0u;
        }
      } else if (tid < CHPAD) {
        chunk[tid] = 0u;
      }
    }
    __syncthreads();
    // P3+P4 fused on wave 0: super-chunk sums, suffix scans, D-scan, and
    // exclusive-suffix conversion — all via shfl/ballot.
    if (tid < 64) {
      int lane = tid;
      unsigned h2 = 0;
      if (lane < CH2N) {
        int cb = lane * 8;
#pragma unroll
        for (int j = 0; j < 8; ++j) h2 += chunk[cb + j];
      }
      unsigned s2 = wave_suffix_sum(h2, lane);
      unsigned long long bal = __ballot((int)(lane < CH2N && s2 >= (unsigned)TOPK));
      int t2 = bal ? (63 - (int)__clzll(bal)) : -1;
      if (t2 < 0 && L16x > 1u) {
        if (lane == 0) ctl_redo = 1;   // filtered total < TOPK: redo unfiltered
      } else {
        if (t2 < 0) {
          // genuinely sparse: fewer than TOPK nonzero keys (total = s2 @ lane 0)
          if (lane == 0) {
            ctl_lo = 1; ctl_hi = 0; ctl_n1 = (int)s2; ctl_kneed = TOPK - (int)s2;
          }
        } else {
          unsigned cumS = (unsigned)__shfl((int)(s2 - h2), t2);  // count(>super t2)
          unsigned hc = (lane < 8) ? chunk[t2 * 8 + lane] : 0u;
          unsigned sc = wave_suffix_sum(hc, lane);
          unsigned long long balc =
              __ballot((int)(lane < 8 && cumS + sc >= (unsigned)TOPK));
          int jc = 63 - (int)__clzll(balc);
          int tc = t2 * 8 + jc;
          unsigned cumC = cumS + (unsigned)__shfl((int)(sc - hc), jc);
          unsigned hb = (lane < 4) ? hist[tc * 4 + lane] : 0u;
          unsigned sb = wave_suffix_sum(hb, lane);
          unsigned long long balb =
              __ballot((int)(lane < 4 && cumC + sb >= (unsigned)TOPK));
          int jb = 63 - (int)__clzll(balb);
          int D = tc * 4 + jb;
          unsigned cum = cumC + (unsigned)__shfl((int)(sb - hb), jb);  // count(>D)
          int hi_ = (D + 1 < HSIZE) ? D + 1 : D;
          int lo_ = (D - 1 >= 1) ? D - 1 : D;
          unsigned hup = (hi_ > D) ? hist[hi_] : 0u;
          if (lane == 0) {
            ctl_lo = lo_; ctl_hi = hi_;
            ctl_n1 = (int)(cum - hup);        // count(buckets > hi)
            ctl_kneed = TOPK - ctl_n1;
          }
        }
        if (lane < 32) chunk2[lane] = s2 - h2;   // exclusive suffix (super level)
      }
    }
    __syncthreads();
    if (!ctl_redo) break;
    L16x = 1u;
  }
  lo = ctl_lo; hi = ctl_hi; n1 = ctl_n1; kneed = ctl_kneed;

  // ---- P5: per-bucket suffix sums: suf[x] = #keys in buckets > x. Entries
  //      below L's chunk are garbage but never read (reads at x >= lo). ----
  if (tid < CHN) {
    unsigned s = chunk2[tid >> 3];
    int ge = ((tid >> 3) + 1) << 3;
    for (int u = tid + 1; u < ge; ++u) s += chunk[u];  // padded zeros safe
    int b0 = tid * 4;
    unsigned h3 = hist[b0 + 3], h2 = hist[b0 + 2], h1 = hist[b0 + 1];
    u3.suf[b0 + 3] = s;
    u3.suf[b0 + 2] = s + h3;
    u3.suf[b0 + 1] = s + h3 + h2;
    u3.suf[b0 + 0] = s + h3 + h2 + h1;
  }
  __syncthreads();

  // ---- P7: collect (stream from L1/L2). Certain (bucket > hi): direct to
  //      final bucket span via atomicSub cursor on hist. Boundary band
  //      [lo..hi] -> bndi (data-driven key compare: L-filter cannot lose
  //      band members). ----
  {
    unsigned tC16 = (unsigned)(0x3C00 + hi);   // key16 >= tC16 <=> bucket > hi
    unsigned tB16 = (unsigned)(0x3BFF + lo);   // key16 >= tB16 <=> bucket >= lo
    for (int q = tid; q < NV; q += 256) {
      uint4 v = sv[q];
      unsigned ks[8] = {v.x & 0xFFFFu, v.x >> 16, v.y & 0xFFFFu, v.y >> 16,
                        v.z & 0xFFFFu, v.z >> 16, v.w & 0xFFFFu, v.w >> 16};
#pragma unroll
      for (int t = 0; t < 8; ++t) {
        unsigned key = ks[t];
        if (key >= tC16) {
          int x = (int)key - 0x3BFF;
          int slot = (int)u3.suf[x] + (int)atomicSub(&hist[x], 1u) - 1;
          if (slot < TOPK) isel[slot] = (x << 16) | (q * 8 + t);  // packed
        } else if (key >= tB16) {
          int p = atomicAdd(&ctl_m, 1);
          if (p < BCAP) u2.bb.bndi[p] = q * 8 + t;
        }
      }
    }
  }
  __syncthreads();
  int m = (hi > 0) ? ctl_m : 0;

  if (hi > 0 && m > BCAP) {
    // ---- overflow fallback: exact 2-pass u16 radix + full bitonic (~never) ----
    if (tid == 0) { ctl_k = TOPK; ctl_pref = 0u; }
    __syncthreads();
    for (int shift = 8; shift >= 0; shift -= 8) {
      hist[tid] = 0u;
      __syncthreads();
      unsigned pref = ctl_pref;
      for (int q = tid; q < NV; q += 256) {
        uint4 v = sv[q];
        unsigned ks[8] = {v.x & 0xFFFFu, v.x >> 16, v.y & 0xFFFFu, v.y >> 16,
                          v.z & 0xFFFFu, v.z >> 16, v.w & 0xFFFFu, v.w >> 16};
#pragma unroll
        for (int t = 0; t < 8; ++t) {
          unsigned key = ks[t];
          if (key == 0u) continue;
          bool match = (shift == 8) || ((key >> 8) == (pref >> 8));
          if (match) atomicAdd(&hist[(key >> shift) & 255u], 1u);
        }
      }
      __syncthreads();
      if (tid == 0) {
        int k = ctl_k;
        unsigned cum = 0;
        int d = 255;
        for (; d > 0; --d) {
          unsigned h = hist[d];
          if (cum + h >= (unsigned)k) break;
          cum += h;
        }
        ctl_k = k - (int)cum;
        ctl_pref = pref | ((unsigned)d << shift);
      }
      __syncthreads();
    }
    unsigned Tf = ctl_pref;
    kneed = ctl_k;
    n1 = TOPK - kneed;
    if (tid == 0) { ctl_cnt = 0; ctl_m = 0; }
    __syncthreads();
    for (int q = tid; q < NV; q += 256) {
      uint4 v = sv[q];
      unsigned ks[8] = {v.x & 0xFFFFu, v.x >> 16, v.y & 0xFFFFu, v.y >> 16,
                        v.z & 0xFFFFu, v.z >> 16, v.w & 0xFFFFu, v.w >> 16};
#pragma unroll
      for (int t = 0; t < 8; ++t) {
        unsigned key = ks[t];
        if (key > Tf) {
          int p = atomicAdd(&ctl_cnt, 1);
          if (p < 256) isel[p] = q * 8 + t;   // raw idx
        } else if (key == Tf) {
          int p = atomicAdd(&ctl_m, 1);
          if (p < BCAP) u2.bb.bndi[p] = q * 8 + t;
        }
      }
    }
    __syncthreads();
    m = ctl_m;
    if (m > BCAP) m = BCAP;
    for (int q = tid; q < m; q += 256)
      u2.bb.bnds[q] = exact_score(conf, aux, use_aux, b, u2.bb.bndi[q], c);
    __syncthreads();
    for (int q = tid; q < m; q += 256) {
      double sq = u2.bb.bnds[q];
      int iq = u2.bb.bndi[q];
      int rank = 0;
      for (int r = 0; r < m; ++r)
        if (entBefore(u2.bb.bnds[r], u2.bb.bndi[r], sq, iq)) ++rank;
      if (rank < kneed) { isel[n1 + rank] = iq; ssel[n1 + rank] = sq; }
    }
    __syncthreads();
    if (tid < TOPK) {
      if (tid < n1) ssel[tid] = exact_score(conf, aux, use_aux, b, isel[tid], c);
    } else {
      ssel[tid] = -1.0;
      isel[tid] = 0x7fffffff;
    }
    // bitonic sort 256: (score desc, index asc)
    for (int kk = 2; kk <= 256; kk <<= 1) {
      for (int j = kk >> 1; j > 0; j >>= 1) {
        __syncthreads();
        int ixj = tid ^ j;
        if (ixj > tid) {
          double s1 = ssel[tid], s2 = ssel[ixj];
          int i1 = isel[tid], i2 = isel[ixj];
          bool up = ((tid & kk) == 0);
          bool sw = up ? entBefore(s2, i2, s1, i1) : entBefore(s1, i1, s2, i2);
          if (sw) {
            ssel[tid] = s2; ssel[ixj] = s1;
            isel[tid] = i2; isel[ixj] = i1;
          }
        }
      }
    }
    __syncthreads();
  } else {
    // ---- main path: sort-free ranking ----
    // P8a: exact scores. certain at temp slot tid (<n1); boundary into bnds.
    if (tid < n1)
      ssel[tid] = exact_score(conf, aux, use_aux, b, isel[tid] & 0xFFFF, c);
    if (hi > 0) {
      for (int q = tid; q < m; q += 256)
        u2.bb.bnds[q] = exact_score(conf, aux, use_aux, b, u2.bb.bndi[q], c);
    }
    __syncthreads();
    // P8b: ranks. Certain: within-bucket exact rank (reads ssel/isel [0,n1)).
    //      Boundary: exact rank among m, writes [n1,200) (disjoint region).
    double myS = 0.0;
    int myI = 0, myPos = -1;
    if (tid < n1) {
      int packed = isel[tid];
      int bk = packed >> 16;
      myI = packed & 0xFFFF;
      myS = ssel[tid];
      int base = (int)u3.suf[bk];
      int len = (int)u3.suf[bk - 1] - base;
      int r = 0;
      for (int u = base; u < base + len; ++u) {
        if (u == tid) continue;
        double ps = ssel[u];
        int pI = isel[u] & 0xFFFF;
        if (entBefore(ps, pI, myS, myI)) ++r;
      }
      myPos = base + r;
    }
    if (hi > 0) {
      for (int q = tid; q < m; q += 256) {
        double sq = u2.bb.bnds[q];
        int iq = u2.bb.bndi[q];
        int rank = 0;
        for (int r = 0; r < m; ++r)
          if (entBefore(u2.bb.bnds[r], u2.bb.bndi[r], sq, iq)) ++rank;
        if (rank < kneed) { isel[n1 + rank] = iq; ssel[n1 + rank] = sq; }
      }
    } else {
      // sparse: zero-score dummies (keep=false downstream -> zero rows)
      for (int j = n1 + tid; j < TOPK; j += 256) {
        isel[j] = j - n1;
        ssel[j] = 0.0;
      }
    }
    __syncthreads();
    // P8c: certain final placement (exact within-bucket order)
    if (myPos >= 0 && myPos < TOPK) { ssel[myPos] = myS; isel[myPos] = myI; }
    __syncthreads();
    // P8d: exact-order guard. Inversions possible only for exact scores within
    // key error (~4e-6 rel) of a bucket edge; detect and (rarely) fix.
    if (tid < 64) {
      bool inv = false;
      for (int j = tid + 1; j < TOPK; j += 64)
        if (entBefore(ssel[j], isel[j], ssel[j - 1], isel[j - 1])) inv = true;
      unsigned long long bal = __ballot((int)inv);
      if (tid == 0 && bal != 0ull) ctl_fix = 1;
    }
    __syncthreads();
    if (ctl_fix) {
      if (tid == 0) {
        for (int a = 1; a < TOPK; ++a) {
          double s = ssel[a];
          int ii = isel[a];
          int p = a - 1;
          while (p >= 0 && entBefore(s, ii, ssel[p], isel[p])) {
            ssel[p + 1] = ssel[p]; isel[p + 1] = isel[p]; --p;
          }
          ssel[p + 1] = s; isel[p + 1] = ii;
        }
      }
      __syncthreads();
    }
  }

  // ---- decode own box: f32 for output/tier-1 (HW expf; matches f32
  //      reference op order -> absmax 0) AND parallel f64 to LDS dbox for
  //      the exact NMS guard (R5/R10-proven: guard = 8 LDS reads). ----
  float fx1 = 0, fy1 = 0, fx2 = 0, fy2 = 0;
  if (tid < TOPK) {
    int ai = isel[tid];
    const float* lp = loc + ((size_t)b * NA + ai) * 4;
    const float* ap = anchors + (size_t)ai * 4;
    float l0 = lp[0], l1 = lp[1], l2 = lp[2], l3 = lp[3];
    float a0 = ap[0], a1 = ap[1], a2 = ap[2], a3 = ap[3];
    float cx = a0 + (l0 * 0.1f) * a2;
    float cy = a1 + (l1 * 0.1f) * a3;
    float w = a2 * expf(l2 * 0.2f);
    float h = a3 * expf(l3 * 0.2f);
    fx1 = cx - 0.5f * w; fy1 = cy - 0.5f * h;
    fx2 = cx + 0.5f * w; fy2 = cy + 0.5f * h;
    u3.fb.fbox[tid] = make_float4(fx1, fy1, fx2, fy2);
    u3.fb.farea[tid] = (fx2 - fx1) * (fy2 - fy1);
    // f64 decode (reuses loaded lp/ap; software exps run in parallel
    // across 200 threads, once per block)
    double dcx = (double)a0 + ((double)l0 * 0.1) * (double)a2;
    double dcy = (double)a1 + ((double)l1 * 0.1) * (double)a3;
    double dw = (double)a2 * exp((double)l2 * 0.2);
    double dh = (double)a3 * exp((double)l3 * 0.2);
    u2.dbox[tid][0] = dcx - 0.5 * dw;
    u2.dbox[tid][1] = dcy - 0.5 * dh;
    u2.dbox[tid][2] = dcx + 0.5 * dw;
    u2.dbox[tid][3] = dcy + 0.5 * dh;
  }
  __syncthreads();

  // ---- lazy greedy NMS on wave 0: alive-mask ballots, jump to next kept
  //      row, IoU on the fly. Kept-box area recomputed from fbox registers
  //      (bit-identical to farea). f32 mult-compare; tight cases decided in
  //      exact f64 from LDS dbox. ----
  if (tid < 64) {
    int l = tid;
    unsigned kr = 0u;
    float4 ob[4]; float oa[4];
#pragma unroll
    for (int q = 0; q < 4; ++q) {
      int j = l + 64 * q;
      if (j < TOPK) {
        if (ssel[j] > CONF_T) kr |= 1u << q;
        ob[q] = u3.fb.fbox[j];
        oa[q] = u3.fb.farea[j];
      } else {
        ob[q] = make_float4(0.0f, 0.0f, 0.0f, 0.0f);
        oa[q] = 0.0f;
      }
    }
    int cur = 0;
    while (cur < TOPK) {
      unsigned long long ms0 = __ballot((int)(kr & 1u));
      unsigned long long ms1 = __ballot((int)(kr & 2u));
      unsigned long long ms2 = __ballot((int)(kr & 4u));
      unsigned long long ms3 = __ballot((int)(kr & 8u));
      int q0 = cur >> 6;
      int sh = cur & 63;
      unsigned long long below = sh ? ((1ull << sh) - 1ull) : 0ull;
      unsigned long long t0 = (q0 == 0) ? (ms0 & ~below) : 0ull;
      unsigned long long t1 = (q0 < 1) ? ms1 : ((q0 == 1) ? (ms1 & ~below) : 0ull);
      unsigned long long t2 = (q0 < 2) ? ms2 : ((q0 == 2) ? (ms2 & ~below) : 0ull);
      unsigned long long t3 = (q0 < 3) ? ms3 : (ms3 & ~below);
      int i = TOPK;
      if (t0) i = __ffsll(t0) - 1;
      else if (t1) i = 64 + __ffsll(t1) - 1;
      else if (t2) i = 128 + __ffsll(t2) - 1;
      else if (t3) i = 192 + __ffsll(t3) - 1;
      if (i >= TOPK) break;          // no alive row left
      float4 fbi = u3.fb.fbox[i];    // LDS broadcast (single b128 read)
      float fai = (fbi.z - fbi.x) * (fbi.w - fbi.y);   // == farea[i] bitwise
#pragma unroll
      for (int q = 0; q < 4; ++q) {
        int r = l + 64 * q;
        if (r > i && r < TOPK && ((kr >> q) & 1u)) {
          float lx = fmaxf(fbi.x, ob[q].x), ly = fmaxf(fbi.y, ob[q].y);
          float rx = fminf(fbi.z, ob[q].z), ry = fminf(fbi.w, ob[q].w);
          float iw = fmaxf(rx - lx, 0.0f), ih = fmaxf(ry - ly, 0.0f);
          float inter = iw * ih;
          float uni = fai + oa[q] - inter + 1e-12f;
          float diff = inter - 0.045f * uni;    // sign(diff) == sign(io-T)
          bool sup;
          if (fabsf(diff) < 3e-4f * uni) {      // |io-T| < 3e-4: decide in f64
            double ix1 = u2.dbox[i][0], iy1 = u2.dbox[i][1];
            double ix2 = u2.dbox[i][2], iy2 = u2.dbox[i][3];
            double jx1 = u2.dbox[r][0], jy1 = u2.dbox[r][1];
            double jx2 = u2.dbox[r][2], jy2 = u2.dbox[r][3];
            double dlx = fmax(ix1, jx1), dly = fmax(iy1, jy1);
            double drx = fmin(ix2, jx2), dry = fmin(iy2, jy2);
            double diw = drx - dlx; if (diw < 0.0) diw = 0.0;
            double dih = dry - dly; if (dih < 0.0) dih = 0.0;
            double dint = diw * dih;
            double dai = (ix2 - ix1) * (iy2 - iy1);
            double daj = (jx2 - jx1) * (jy2 - jy1);
            sup = dint > NMS_T * (dai + daj - dint + 1e-12);
          } else {
            sup = diff > 0.0f;
          }
          if (sup) kr &= ~(1u << q);
        }
      }
      cur = i + 1;
    }
#pragma unroll
    for (int q = 0; q < 4; ++q) {
      unsigned long long bal = __ballot((int)((kr >> q) & 1u));
      if (l == 0) {
        keepw[2 * q] = (unsigned)bal;
        if (2 * q + 1 < 7) keepw[2 * q + 1] = (unsigned)(bal >> 32);
      }
    }
  }
  __syncthreads();

  // ---- pack kept rows to the front, zero-fill the rest ----
  int nk = 0;
#pragma unroll
  for (int w = 0; w < 7; ++w) nk += __popc(keepw[w]);
  if (tid < TOPK) {
    int j = tid;
    bool kept = (keepw[j >> 5] >> (j & 31)) & 1u;
    if (kept) {
      int pos = 0;
      for (int w = 0; w < (j >> 5); ++w) pos += __popc(keepw[w]);
      pos += __popc(keepw[j >> 5] & ((1u << (j & 31)) - 1u));
      float* o = outbase + (size_t)pos * 5;
      o[0] = (float)ssel[j];
      o[1] = fx1;
      o[2] = fy1;
      o[3] = fx2;
      o[4] = fy2;
    }
    if (j >= nk) {
      float* o = outbase + (size_t)j * 5;
      o[0] = 0.0f; o[1] = 0.0f; o[2] = 0.0f; o[3] = 0.0f; o[4] = 0.0f;
    }
  }
}

// ===========================================================================
// Tiny-workspace fallback (R2-proven, self-contained) — only if ws too small
// ===========================================================================
__global__ __launch_bounds__(256) void k_main_nf(const float* __restrict__ loc,
                                                 const float* __restrict__ conf,
                                                 const float* __restrict__ anchors,
                                                 float* __restrict__ out) {
  int bc = blockIdx.x;
  int b = bc / NC;
  int c = bc % NC;
  int tid = threadIdx.x;
  float* outbase = out + (size_t)bc * TOPK * 5;
  if (c == 0) {
    for (int k = tid; k < TOPK * 5; k += 256) outbase[k] = 0.0f;
    return;
  }
  union U {
    float sf[NA];
    struct { double box[TOPK][4]; double area[TOPK]; } p2;
  };
  __shared__ U u;
  __shared__ double ssel[256];
  __shared__ int isel[256];
  __shared__ unsigned hist[256];
  __shared__ double bnds[256];
  __shared__ int bndi[256];
  __shared__ int keepL[256];
  __shared__ unsigned long long wmask[4];
  __shared__ int ctl_k, ctl_cnt, ctl_m;
  __shared__ unsigned ctl_pref;

  for (int i = tid; i < NA; i += 256)
    u.sf[i] = (float)exact_score_cf(conf, b, i, c);
  if (tid == 0) { ctl_k = TOPK; ctl_pref = 0u; }
  __syncthreads();
  for (int shift = 24; shift >= 0; shift -= 8) {
    hist[tid] = 0u;
    __syncthreads();
    unsigned pref = ctl_pref;
    for (int i = tid; i < NA; i += 256) {
      unsigned key = __float_as_uint(u.sf[i]);
      bool match = (shift == 24) || ((key >> (shift + 8)) == (pref >> (shift + 8)));
      if (match) atomicAdd(&hist[(key >> shift) & 255u], 1u);
    }
    __syncthreads();
    if (tid == 0) {
      int k = ctl_k;
      unsigned cum = 0;
      int d = 255;
      for (; d > 0; --d) {
        unsigned h = hist[d];
        if (cum + h >= (unsigned)k) break;
        cum += h;
      }
      ctl_k = k - (int)cum;
      ctl_pref = pref | ((unsigned)d << shift);
    }
    __syncthreads();
  }
  unsigned Tf = ctl_pref;
  int kneed = ctl_k;
  int n1 = TOPK - kneed;
  if (tid == 0) { ctl_cnt = 0; ctl_m = 0; }
  __syncthreads();
  for (int i = tid; i < NA; i += 256) {
    unsigned key = __float_as_uint(u.sf[i]);
    if (key > Tf) {
      int p = atomicAdd(&ctl_cnt, 1);
      if (p < 256) isel[p] = i;
    } else if (key == Tf && Tf != 0u) {
      int q = atomicAdd(&ctl_m, 1);
      if (q < 256) bndi[q] = i;
    }
  }
  __syncthreads();
  int zf;
  if (Tf == 0u) {
    zf = n1;
    for (int j = n1 + tid; j < TOPK; j += 256) isel[j] = j - n1;
  } else {
    zf = TOPK;
    int m = ctl_m;
    if (m > 256) m = 256;
    if (tid < m) bnds[tid] = exact_score_cf(conf, b, bndi[tid], c);
    __syncthreads();
    if (tid < m) {
      double sq = bnds[tid];
      int iq = bndi[tid];
      int rank = 0;
      for (int r = 0; r < m; ++r)
        if (entBefore(bnds[r], bndi[r], sq, iq)) ++rank;
      if (rank < kneed) isel[n1 + rank] = iq;
    }
  }
  __syncthreads();
  if (tid < TOPK) {
    ssel[tid] = (tid < zf) ? exact_score_cf(conf, b, isel[tid], c) : 0.0;
  } else {
    ssel[tid] = -1.0;
    isel[tid] = 0x7fffffff;
  }
  for (int kk = 2; kk <= 256; kk <<= 1) {
    for (int j = kk >> 1; j > 0; j >>= 1) {
      __syncthreads();
      int ixj = tid ^ j;
      if (ixj > tid) {
        double s1 = ssel[tid], s2 = ssel[ixj];
        int i1 = isel[tid], i2 = isel[ixj];
        bool up = ((tid & kk) == 0);
        bool sw = up ? entBefore(s2, i2, s1, i1) : entBefore(s1, i1, s2, i2);
        if (sw) {
          ssel[tid] = s2; ssel[ixj] = s1;
          isel[tid] = i2; isel[ixj] = i1;
        }
      }
    }
  }
  __syncthreads();
  if (tid < TOPK) {
    double bx[4];
    decode64(loc, anchors, b, isel[tid], bx);
    u.p2.box[tid][0] = bx[0]; u.p2.box[tid][1] = bx[1];
    u.p2.box[tid][2] = bx[2]; u.p2.box[tid][3] = bx[3];
    u.p2.area[tid] = (bx[2] - bx[0]) * (bx[3] - bx[1]);
  }
  __syncthreads();
  double mx1 = 0, my1 = 0, mx2 = 0, my2 = 0, mar = 0;
  if (tid < TOPK) {
    mx1 = u.p2.box[tid][0]; my1 = u.p2.box[tid][1];
    mx2 = u.p2.box[tid][2]; my2 = u.p2.box[tid][3];
    mar = u.p2.area[tid];
  }
  keepL[tid] = (tid < TOPK) && (ssel[tid] > CONF_T);
  __syncthreads();
  for (int i = 0; i < TOPK; ++i) {
    int ki = keepL[i];
    if (ki && tid > i && tid < TOPK && keepL[tid]) {
      double lx = fmax(u.p2.box[i][0], mx1);
      double ly = fmax(u.p2.box[i][1], my1);
      double rx = fmin(u.p2.box[i][2], mx2);
      double ry = fmin(u.p2.box[i][3], my2);
      double iw = rx - lx; if (iw < 0.0) iw = 0.0;
      double ih = ry - ly; if (ih < 0.0) ih = 0.0;
      double inter = iw * ih;
      double iou = inter / (u.p2.area[i] + mar - inter + 1e-12);
      if (iou > NMS_T) keepL[tid] = 0;
    }
    __syncthreads();
  }
  bool kj = (tid < TOPK) && (keepL[tid] != 0);
  unsigned long long bal = __ballot((int)kj);
  int wave = tid >> 6, lane = tid & 63;
  if (lane == 0) wmask[wave] = bal;
  __syncthreads();
  int nk = 0;
#pragma unroll
  for (int w = 0; w < 4; ++w) nk += __popcll(wmask[w]);
  if (kj) {
    int pos = 0;
    for (int w = 0; w < wave; ++w) pos += __popcll(wmask[w]);
    pos += __popcll(bal & ((1ull << lane) - 1ull));
    float* o = outbase + (size_t)pos * 5;
    o[0] = (float)ssel[tid];
    o[1] = (float)u.p2.box[tid][0];
    o[2] = (float)u.p2.box[tid][1];
    o[3] = (float)u.p2.box[tid][2];
    o[4] = (float)u.p2.box[tid][3];
  }
  if (tid < TOPK && tid >= nk) {
    float* o = outbase + (size_t)tid * 5;
    o[0] = 0.0f; o[1] = 0.0f; o[2] = 0.0f; o[3] = 0.0f; o[4] = 0.0f;
  }
}

// ---------------------------------------------------------------------------
extern "C" void kernel_launch(void* const* d_in, const int* in_sizes, int n_in,
                              void* d_out, int out_size, void* d_ws, size_t ws_size,
                              hipStream_t stream) {
  const float* loc = (const float*)d_in[0];
  const float* conf = (const float*)d_in[1];
  const float* anchors = (const float*)d_in[2];
  float* out = (float*)d_out;

  const size_t SC_BYTES = (size_t)NB * (NC - 1) * NAP * sizeof(unsigned short);  // 44.7 MB
  const size_t AUX_BYTES = (size_t)NB * NA * sizeof(double2);                    // 17.9 MB

  if (ws_size >= SC_BYTES + AUX_BYTES) {
    unsigned short* scores = (unsigned short*)d_ws;
    double2* aux = (double2*)((char*)d_ws + SC_BYTES);   // 16B-aligned (SC_BYTES%16==0)
    k_prep<<<(NB * NA) / 256, 256, 0, stream>>>(conf, scores, aux, out, 1);
    k_fast<<<NB * (NC - 1), 256, 0, stream>>>(loc, conf, anchors, scores, aux, out, 1);
  } else if (ws_size >= SC_BYTES) {
    unsigned short* scores = (unsigned short*)d_ws;
    k_prep<<<(NB * NA) / 256, 256, 0, stream>>>(conf, scores, nullptr, out, 0);
    k_fast<<<NB * (NC - 1), 256, 0, stream>>>(loc, conf, anchors, scores, nullptr, out, 0);
  } else {
    k_main_nf<<<NB * NC, 256, 0, stream>>>(loc, conf, anchors, out);
  }
}